// Round 2
// baseline (7424.805 us; speedup 1.0000x reference)
//
#include <hip/hip_runtime.h>
#include <hip/hip_bf16.h>
#include <stdint.h>

#define NDIM   64     // node channels D
#define MDIM   16     // msg channels
#define NLAYER 3
#define EIN    129    // 2D+1
#define EHD    258    // edge hidden
#define CHD    64     // coord hidden
#define NHD    128    // node hidden
#define NIN    80     // D + M
#define ABSTR  528    // AB row stride (elems). A' in [0,264), B in [264,528)
#define AHALF  264
#define KPAIR  132    // 264/2 packed k-pairs

typedef float vf2 __attribute__((ext_vector_type(2)));

__device__ __forceinline__ float rcp_f(float x) { return __builtin_amdgcn_rcpf(x); }
__device__ __forceinline__ float silu_f(float v) {
    // v * sigmoid(v) with approx rcp (v_rcp_f32) instead of IEEE div
    return v * rcp_f(1.0f + __expf(-v));
}
__device__ __forceinline__ float bflo(uint32_t u) {
    union { uint32_t u; float f; } c; c.u = u << 16; return c.f;
}
__device__ __forceinline__ float bfhi(uint32_t u) {
    union { uint32_t u; float f; } c; c.u = u & 0xffff0000u; return c.f;
}
__device__ __forceinline__ uint32_t f2bf_rne(float f) {
    uint32_t u = __float_as_uint(f);
    return (u + 0x7fffu + ((u >> 16) & 1u)) >> 16;
}

// ---------------- prep: transpose / pad weights once per call ----------------
__global__ void prep_kernel(const float* __restrict__ We1, const float* __restrict__ be1,
                            const float* __restrict__ Wn1,
                            float* __restrict__ Wtg, float* __restrict__ biasAB,
                            float* __restrict__ Wn1t) {
    int idx = blockIdx.x * 256 + threadIdx.x;
    const int wtg_total = NLAYER * 66 * 64 * 8;   // 101376
    if (idx < wtg_total) {
        int l  = idx / 33792;
        int r  = idx % 33792;
        int jg = r / 512;
        int k  = (r % 512) / 8;
        int i  = r % 8;
        int j  = jg * 8 + i;
        float v = 0.f;
        if (j < EHD)                       v = We1[((size_t)l * EIN + k) * EHD + j];
        else if (j >= AHALF && j < AHALF + EHD)
                                           v = We1[((size_t)l * EIN + 64 + k) * EHD + (j - AHALF)];
        Wtg[idx] = v;
        return;
    }
    int idx2 = idx - wtg_total;
    if (idx2 < NLAYER * ABSTR) {
        int l = idx2 / ABSTR, j = idx2 % ABSTR;
        biasAB[idx2] = (j < EHD) ? be1[l * EHD + j] : 0.f;
        return;
    }
    int idx3 = idx2 - NLAYER * ABSTR;
    if (idx3 < NLAYER * NHD * NIN) {
        int l = idx3 / (NHD * NIN);
        int r = idx3 % (NHD * NIN);
        int j = r / NIN;
        int k = r % NIN;
        Wn1t[idx3] = Wn1[((size_t)l * NIN + k) * NHD + j];
    }
}

// ---------------- init: embedding lookup + pos copy ----------------
__global__ void init_kernel(const int* __restrict__ feats, const float* __restrict__ coors,
                            const float* __restrict__ emb,
                            float* __restrict__ x, float* __restrict__ pos, int N) {
    int idx = blockIdx.x * 256 + threadIdx.x;
    int nx = N * NDIM;
    if (idx < nx) {
        int n = idx >> 6, c = idx & 63;
        x[idx] = emb[feats[n] * NDIM + c];
    } else {
        int j = idx - nx;
        if (j < N * 3) pos[j] = coors[j];
    }
}

// ---------------- per-node AB GEMM: AB[n] = [x@We1_top + be1 | x@We1_bot] (bf16) ----------
__global__ void __launch_bounds__(256) gemm_ab_kernel(
        const float* __restrict__ x, const float* __restrict__ Wtg,
        const float* __restrict__ biasAB, uint16_t* __restrict__ AB, int N) {
    int n = blockIdx.x * 256 + threadIdx.x;
    if (n >= N) return;
    float xr[64];
    const float4* xp = (const float4*)(x + (size_t)n * NDIM);
    #pragma unroll
    for (int q = 0; q < 16; ++q) {
        float4 v = xp[q];
        xr[4*q] = v.x; xr[4*q+1] = v.y; xr[4*q+2] = v.z; xr[4*q+3] = v.w;
    }
    uint16_t* out = AB + (size_t)n * ABSTR;
    for (int jg = 0; jg < 66; ++jg) {
        float acc[8];
        #pragma unroll
        for (int i = 0; i < 8; ++i) acc[i] = biasAB[jg * 8 + i];
        const float4* wp = (const float4*)(Wtg + (size_t)jg * 512);
        #pragma unroll
        for (int k = 0; k < 64; ++k) {        // full unroll -> xr[k] static
            float4 w0 = wp[2*k], w1 = wp[2*k+1];
            float xv = xr[k];
            acc[0] += xv * w0.x; acc[1] += xv * w0.y; acc[2] += xv * w0.z; acc[3] += xv * w0.w;
            acc[4] += xv * w1.x; acc[5] += xv * w1.y; acc[6] += xv * w1.z; acc[7] += xv * w1.w;
        }
        uint4 pk;
        pk.x = f2bf_rne(acc[0]) | (f2bf_rne(acc[1]) << 16);
        pk.y = f2bf_rne(acc[2]) | (f2bf_rne(acc[3]) << 16);
        pk.z = f2bf_rne(acc[4]) | (f2bf_rne(acc[5]) << 16);
        pk.w = f2bf_rne(acc[6]) | (f2bf_rne(acc[7]) << 16);
        *(uint4*)(out + jg * 8) = pk;
    }
}

// ---------------- per-edge fused message + coord + scatter (packed f32) ----------------
__global__ void __launch_bounds__(256) edge_kernel(
        const int* __restrict__ ei, const float* __restrict__ pos,
        const uint16_t* __restrict__ AB,
        const float* __restrict__ We2, const float* __restrict__ be2,
        const float* __restrict__ Wc1, const float* __restrict__ bc1,
        const float* __restrict__ Wc2, const float* __restrict__ bc2,
        const float* __restrict__ w128,
        float* __restrict__ agg_msg, float* __restrict__ agg_pos, int E) {

    // Packed-pair LDS layouts: index kp pairs consecutive k = (2kp, 2kp+1)
    __shared__ __align__(16) vf2   We2p[KPAIR * MDIM];   // [132][16] {W[2kp][m], W[2kp+1][m]}
    __shared__ __align__(16) vf2   w128p[KPAIR];
    __shared__ __align__(16) float Wc1s[MDIM * CHD];     // [16][64] natural pairing over c
    __shared__ __align__(16) float bc1s[CHD];
    __shared__ __align__(16) float Wc2s[CHD];
    __shared__ float be2s[MDIM];
    __shared__ float bc2s;

    // ---- hoist per-edge index/gather loads above staging to overlap latency ----
    int e = blockIdx.x * 256 + threadIdx.x;
    bool active = (e < E);
    int ec = active ? e : 0;
    int s = ei[ec];
    int t = ei[E + ec];

    float px_t = pos[3*t], py_t = pos[3*t+1], pz_t = pos[3*t+2];
    float px_s = pos[3*s], py_s = pos[3*s+1], pz_s = pos[3*s+2];

    const uint4* arow = (const uint4*)(AB + (size_t)t * ABSTR);          // A' (tgt)
    const uint4* brow = (const uint4*)(AB + (size_t)s * ABSTR + AHALF);  // B  (src)
    uint4 a = arow[0];
    uint4 b = brow[0];

    // ---- stage weights to LDS ----
    for (int i = threadIdx.x; i < KPAIR * MDIM; i += 256) {
        int kp = i >> 4, m = i & 15;
        int k0 = kp * 2;
        float lo = (k0     < EHD) ? We2[k0 * MDIM + m]       : 0.f;
        float hi = (k0 + 1 < EHD) ? We2[(k0 + 1) * MDIM + m] : 0.f;
        We2p[i] = (vf2){lo, hi};
    }
    for (int i = threadIdx.x; i < KPAIR; i += 256) {
        int k0 = i * 2;
        float lo = (k0     < EHD) ? w128[k0]     : 0.f;
        float hi = (k0 + 1 < EHD) ? w128[k0 + 1] : 0.f;
        w128p[i] = (vf2){lo, hi};
    }
    for (int i = threadIdx.x; i < MDIM * CHD; i += 256) Wc1s[i] = Wc1[i];
    if (threadIdx.x < CHD) { bc1s[threadIdx.x] = bc1[threadIdx.x]; Wc2s[threadIdx.x] = Wc2[threadIdx.x]; }
    if (threadIdx.x < MDIM) be2s[threadIdx.x] = be2[threadIdx.x];
    if (threadIdx.x == 0) bc2s = bc2[0];
    __syncthreads();
    if (!active) return;

    float rx = px_t - px_s;
    float ry = py_t - py_s;
    float rz = pz_t - pz_s;
    float d2 = rx*rx + ry*ry + rz*rz;
    vf2 d2v = (vf2){d2, d2};

    vf2 macc[MDIM];
    #pragma unroll
    for (int m = 0; m < MDIM; ++m) macc[m] = (vf2){0.f, 0.f};

    // kc loop with 1-deep prefetch. Over-read at kc=32 is in-bounds:
    // arow[33] = B-half of same node; brow[33] = next node's row (or agg_msg scratch).
    for (int kc = 0; kc < 33; ++kc) {
        uint4 an = arow[kc + 1];
        uint4 bn = brow[kc + 1];
        uint32_t au[4] = {a.x, a.y, a.z, a.w};
        uint32_t bu[4] = {b.x, b.y, b.z, b.w};
        #pragma unroll
        for (int q = 0; q < 4; ++q) {
            int kp = kc * 4 + q;
            vf2 av = (vf2){bflo(au[q]), bfhi(au[q])};
            vf2 bv = (vf2){bflo(bu[q]), bfhi(bu[q])};
            vf2 pre = av + bv + d2v * w128p[kp];
            vf2 h;
            h.x = silu_f(pre.x);
            h.y = silu_f(pre.y);
            const vf2* wrow = &We2p[kp * MDIM];
            #pragma unroll
            for (int m = 0; m < MDIM; ++m) macc[m] += h * wrow[m];  // v_pk_fma_f32
        }
        a = an; b = bn;
    }

    float msg[MDIM];
    vf2 msp[MDIM];
    #pragma unroll
    for (int m = 0; m < MDIM; ++m) {
        msg[m] = silu_f(be2s[m] + macc[m].x + macc[m].y);
        msp[m] = (vf2){msg[m], msg[m]};
    }

    // coord MLP, pair-packed over c
    const vf2* bc1v = (const vf2*)bc1s;
    const vf2* wc2v = (const vf2*)Wc2s;
    vf2 cwacc = (vf2){0.f, 0.f};
    #pragma unroll 4
    for (int cp = 0; cp < CHD / 2; ++cp) {
        vf2 tacc = bc1v[cp];
        #pragma unroll
        for (int m = 0; m < MDIM; ++m) {
            vf2 w = *(const vf2*)&Wc1s[m * CHD + 2 * cp];
            tacc += msp[m] * w;
        }
        vf2 hs;
        hs.x = silu_f(tacc.x);
        hs.y = silu_f(tacc.y);
        cwacc += hs * wc2v[cp];
    }
    float cw = bc2s + cwacc.x + cwacc.y;

    float* am = agg_msg + (size_t)t * MDIM;
    #pragma unroll
    for (int m = 0; m < MDIM; ++m) atomicAdd(&am[m], msg[m]);
    atomicAdd(&agg_pos[3*t],   rx * cw);
    atomicAdd(&agg_pos[3*t+1], ry * cw);
    atomicAdd(&agg_pos[3*t+2], rz * cw);
}

// ---------------- per-node MLP + residual + pos update ----------------
__global__ void __launch_bounds__(256) node_kernel(
        float* __restrict__ x, float* __restrict__ pos,
        const float* __restrict__ agg_msg, const float* __restrict__ agg_pos,
        const float* __restrict__ Wn1t, const float* __restrict__ bn1,
        const float* __restrict__ Wn2, const float* __restrict__ bn2, int N) {
    int n = blockIdx.x * 256 + threadIdx.x;
    if (n >= N) return;
    float in[NIN];
    const float4* xp = (const float4*)(x + (size_t)n * NDIM);
    #pragma unroll
    for (int q = 0; q < 16; ++q) {
        float4 v = xp[q];
        in[4*q] = v.x; in[4*q+1] = v.y; in[4*q+2] = v.z; in[4*q+3] = v.w;
    }
    const float4* mp = (const float4*)(agg_msg + (size_t)n * MDIM);
    #pragma unroll
    for (int q = 0; q < 4; ++q) {
        float4 v = mp[q];
        in[64+4*q] = v.x; in[64+4*q+1] = v.y; in[64+4*q+2] = v.z; in[64+4*q+3] = v.w;
    }
    float out[NDIM];
    #pragma unroll
    for (int o = 0; o < NDIM; ++o) out[o] = bn2[o];
    for (int j = 0; j < NHD; ++j) {
        float t = bn1[j];
        const float4* w1 = (const float4*)(Wn1t + (size_t)j * NIN);
        #pragma unroll
        for (int q = 0; q < 20; ++q) {
            float4 w = w1[q];
            t += in[4*q]*w.x + in[4*q+1]*w.y + in[4*q+2]*w.z + in[4*q+3]*w.w;
        }
        float h = silu_f(t);
        const float4* w2 = (const float4*)(Wn2 + (size_t)j * NDIM);
        #pragma unroll
        for (int q = 0; q < 16; ++q) {
            float4 w = w2[q];
            out[4*q] += h*w.x; out[4*q+1] += h*w.y; out[4*q+2] += h*w.z; out[4*q+3] += h*w.w;
        }
    }
    float4* xo = (float4*)(x + (size_t)n * NDIM);
    #pragma unroll
    for (int q = 0; q < 16; ++q) {
        float4 v;
        v.x = in[4*q]   + out[4*q];
        v.y = in[4*q+1] + out[4*q+1];
        v.z = in[4*q+2] + out[4*q+2];
        v.w = in[4*q+3] + out[4*q+3];
        xo[q] = v;
    }
    pos[3*n]   += agg_pos[3*n];
    pos[3*n+1] += agg_pos[3*n+1];
    pos[3*n+2] += agg_pos[3*n+2];
}

// ---------------- host launch ----------------
extern "C" void kernel_launch(void* const* d_in, const int* in_sizes, int n_in,
                              void* d_out, int out_size, void* d_ws, size_t ws_size,
                              hipStream_t stream) {
    const int*   feats = (const int*)  d_in[0];
    const float* coors = (const float*)d_in[1];
    const int*   ei    = (const int*)  d_in[2];
    const float* emb   = (const float*)d_in[3];
    const float* We1   = (const float*)d_in[4];
    const float* be1   = (const float*)d_in[5];
    const float* We2   = (const float*)d_in[6];
    const float* be2   = (const float*)d_in[7];
    const float* Wc1   = (const float*)d_in[8];
    const float* bc1   = (const float*)d_in[9];
    const float* Wc2   = (const float*)d_in[10];
    const float* bc2   = (const float*)d_in[11];
    const float* Wn1   = (const float*)d_in[12];
    const float* bn1   = (const float*)d_in[13];
    const float* Wn2   = (const float*)d_in[14];
    const float* bn2   = (const float*)d_in[15];

    const int N = in_sizes[0];
    const int E = in_sizes[2] / 2;

    float* x   = (float*)d_out;                     // [N,64]
    float* pos = (float*)d_out + (size_t)N * NDIM;  // [N,3]

    // workspace layout
    char* w = (char*)d_ws;
    uint16_t* AB = (uint16_t*)w;                       // N*528 bf16
    size_t off = ((size_t)N * ABSTR * 2 + 255) & ~(size_t)255;
    float* agg_msg = (float*)(w + off);                // N*16
    off += ((size_t)N * MDIM * 4 + 255) & ~(size_t)255;
    float* agg_pos = (float*)(w + off);                // N*3
    off += ((size_t)N * 3 * 4 + 255) & ~(size_t)255;
    float* Wtg = (float*)(w + off);                    // 3*66*64*8 f32
    off += (size_t)NLAYER * 33792 * 4;
    float* biasAB = (float*)(w + off);                 // 3*528
    off += (size_t)NLAYER * ABSTR * 4;
    float* Wn1t = (float*)(w + off);                   // 3*128*80
    (void)ws_size; (void)n_in; (void)out_size;

    {
        int total = NLAYER * 33792 + NLAYER * ABSTR + NLAYER * NHD * NIN;
        prep_kernel<<<(total + 255) / 256, 256, 0, stream>>>(We1, be1, Wn1, Wtg, biasAB, Wn1t);
    }
    {
        int total = N * (NDIM + 3);
        init_kernel<<<(total + 255) / 256, 256, 0, stream>>>(feats, coors, emb, x, pos, N);
    }

    for (int l = 0; l < NLAYER; ++l) {
        const float* We1_l  = We1 + (size_t)l * EIN * EHD;
        const float* w128_l = We1_l + (size_t)128 * EHD;

        gemm_ab_kernel<<<(N + 255) / 256, 256, 0, stream>>>(
            x, Wtg + (size_t)l * 33792, biasAB + (size_t)l * ABSTR, AB, N);

        hipMemsetAsync(agg_msg, 0, (size_t)N * MDIM * 4, stream);
        hipMemsetAsync(agg_pos, 0, (size_t)N * 3 * 4, stream);

        edge_kernel<<<(E + 255) / 256, 256, 0, stream>>>(
            ei, pos, AB,
            We2 + (size_t)l * EHD * MDIM, be2 + (size_t)l * MDIM,
            Wc1 + (size_t)l * MDIM * CHD, bc1 + (size_t)l * CHD,
            Wc2 + (size_t)l * CHD, bc2 + l, w128_l,
            agg_msg, agg_pos, E);

        node_kernel<<<(N + 255) / 256, 256, 0, stream>>>(
            x, pos, agg_msg, agg_pos,
            Wn1t + (size_t)l * NHD * NIN, bn1 + (size_t)l * NHD,
            Wn2 + (size_t)l * NHD * NDIM, bn2 + (size_t)l * NDIM, N);
    }
}

// Round 3
// 2621.268 us; speedup vs baseline: 2.8325x; 2.8325x over previous
//
#include <hip/hip_runtime.h>
#include <hip/hip_bf16.h>
#include <stdint.h>

#define NDIM   64     // node channels D
#define MDIM   16     // msg channels
#define NLAYER 3
#define EIN    129    // 2D+1
#define EHD    258    // edge hidden
#define CHD    64     // coord hidden
#define NHD    128    // node hidden
#define NIN    80     // D + M
#define KP2    129    // packed k-pairs: 128 fp8 pairs + 1 extras pair
#define AB_STRIDE 512 // bytes per node in fp8 AB table (A 256B | B 256B)
#define PKT_STRIDE 32 // bytes per node packet: pos xyz f32, a2 bf16x2, b2 bf16x2
#define FP8_SCALE 1024.0f
#define FP8_INV   (1.0f/1024.0f)

typedef float vf2 __attribute__((ext_vector_type(2)));

__device__ __forceinline__ float rcp_f(float x) { return __builtin_amdgcn_rcpf(x); }
__device__ __forceinline__ float silu_f(float v) {
    return v * rcp_f(1.0f + __expf(-v));
}
__device__ __forceinline__ float bflo(uint32_t u) {
    union { uint32_t u; float f; } c; c.u = u << 16; return c.f;
}
__device__ __forceinline__ float bfhi(uint32_t u) {
    union { uint32_t u; float f; } c; c.u = u & 0xffff0000u; return c.f;
}
__device__ __forceinline__ uint32_t f2bf_rne(float f) {
    uint32_t u = __float_as_uint(f);
    return (u + 0x7fffu + ((u >> 16) & 1u)) >> 16;
}
__device__ __forceinline__ uint32_t pk_fp8_4(float f0, float f1, float f2, float f3) {
    uint32_t r = (uint32_t)__builtin_amdgcn_cvt_pk_fp8_f32(f0, f1, 0, false);
    r = (uint32_t)__builtin_amdgcn_cvt_pk_fp8_f32(f2, f3, (int)r, true);
    return r;
}
__device__ __forceinline__ float clamp8(float v) {
    return fminf(448.0f, fmaxf(-448.0f, v * FP8_SCALE));
}

// ---------------- prep: transpose / pad weights once per call ----------------
__global__ void prep_kernel(const float* __restrict__ We1, const float* __restrict__ be1,
                            const float* __restrict__ Wn1,
                            float* __restrict__ Wtg, float* __restrict__ biasAB,
                            float* __restrict__ Wn1t) {
    int idx = blockIdx.x * 256 + threadIdx.x;
    const int wtg_total = NLAYER * 66 * 64 * 8;   // 101376
    if (idx < wtg_total) {
        int l  = idx / 33792;
        int r  = idx % 33792;
        int jg = r / 512;
        int k  = (r % 512) / 8;
        int i  = r % 8;
        int j  = jg * 8 + i;
        // j<258: A-part col j; 264<=j<522: B-part col j-264; else 0
        float v = 0.f;
        if (j < EHD)                       v = We1[((size_t)l * EIN + k) * EHD + j];
        else if (j >= 264 && j < 264 + EHD)
                                           v = We1[((size_t)l * EIN + 64 + k) * EHD + (j - 264)];
        Wtg[idx] = v;
        return;
    }
    int idx2 = idx - wtg_total;
    if (idx2 < NLAYER * 528) {
        int l = idx2 / 528, j = idx2 % 528;
        biasAB[idx2] = (j < EHD) ? be1[l * EHD + j] : 0.f;
        return;
    }
    int idx3 = idx2 - NLAYER * 528;
    if (idx3 < NLAYER * NHD * NIN) {
        int l = idx3 / (NHD * NIN);
        int r = idx3 % (NHD * NIN);
        int j = r / NIN;
        int k = r % NIN;
        Wn1t[idx3] = Wn1[((size_t)l * NIN + k) * NHD + j];
    }
}

// ---------------- init: embedding lookup + pos copy ----------------
__global__ void init_kernel(const int* __restrict__ feats, const float* __restrict__ coors,
                            const float* __restrict__ emb,
                            float* __restrict__ x, float* __restrict__ pos, int N) {
    int idx = blockIdx.x * 256 + threadIdx.x;
    int nx = N * NDIM;
    if (idx < nx) {
        int n = idx >> 6, c = idx & 63;
        x[idx] = emb[feats[n] * NDIM + c];
    } else {
        int j = idx - nx;
        if (j < N * 3) pos[j] = coors[j];
    }
}

// ---------------- counting sort by target ----------------
__global__ void hist_kernel(const int* __restrict__ ei, int* __restrict__ cnt, int E) {
    int e = blockIdx.x * 256 + threadIdx.x;
    if (e < E) atomicAdd(&cnt[ei[E + e]], 1);
}

// single-block exclusive scan over N bins -> cursor
__global__ void __launch_bounds__(1024) scan_kernel(const int* __restrict__ cnt,
                                                    int* __restrict__ cursor, int N) {
    __shared__ int wsum[16];
    __shared__ int carry_s;
    int tid = threadIdx.x, lane = tid & 63, w = tid >> 6;
    if (tid == 0) carry_s = 0;
    __syncthreads();
    for (int base = 0; base < N; base += 1024) {
        int i = base + tid;
        int v = (i < N) ? cnt[i] : 0;
        int sc = v;
        #pragma unroll
        for (int off = 1; off < 64; off <<= 1) {
            int u = __shfl_up(sc, off);
            if (lane >= off) sc += u;
        }
        if (lane == 63) wsum[w] = sc;
        __syncthreads();
        int woff = 0;
        #pragma unroll
        for (int k = 0; k < 16; ++k) woff += (k < w) ? wsum[k] : 0;
        int carry = carry_s;
        if (i < N) cursor[i] = carry + woff + sc - v;
        __syncthreads();
        if (tid == 1023) carry_s = carry + woff + sc;
        __syncthreads();
    }
}

__global__ void scatter_kernel(const int* __restrict__ ei, int* __restrict__ cursor,
                               uint2* __restrict__ sorted_st, int E) {
    int e = blockIdx.x * 256 + threadIdx.x;
    if (e >= E) return;
    int s = ei[e], t = ei[E + e];
    int p = atomicAdd(&cursor[t], 1);
    uint2 st; st.x = (uint32_t)s; st.y = (uint32_t)t;
    sorted_st[p] = st;
}

// ---------------- per-node AB GEMM -> fp8 table + node packet ----------------
__global__ void __launch_bounds__(256) gemm_ab_kernel(
        const float* __restrict__ x, const float* __restrict__ pos,
        const float* __restrict__ Wtg, const float* __restrict__ biasAB,
        uint8_t* __restrict__ A8, uint8_t* __restrict__ pkt, int N) {
    int n = blockIdx.x * 256 + threadIdx.x;
    if (n >= N) return;
    float xr[64];
    const float4* xp = (const float4*)(x + (size_t)n * NDIM);
    #pragma unroll
    for (int q = 0; q < 16; ++q) {
        float4 v = xp[q];
        xr[4*q] = v.x; xr[4*q+1] = v.y; xr[4*q+2] = v.z; xr[4*q+3] = v.w;
    }
    uint2* out = (uint2*)(A8 + (size_t)n * AB_STRIDE);
    uint32_t a2 = 0, b2 = 0;
    for (int jg = 0; jg < 66; ++jg) {
        float acc[8];
        #pragma unroll
        for (int i = 0; i < 8; ++i) acc[i] = biasAB[jg * 8 + i];
        const float4* wp = (const float4*)(Wtg + (size_t)jg * 512);
        #pragma unroll
        for (int k = 0; k < 64; ++k) {
            float4 w0 = wp[2*k], w1 = wp[2*k+1];
            float xv = xr[k];
            acc[0] += xv * w0.x; acc[1] += xv * w0.y; acc[2] += xv * w0.z; acc[3] += xv * w0.w;
            acc[4] += xv * w1.x; acc[5] += xv * w1.y; acc[6] += xv * w1.z; acc[7] += xv * w1.w;
        }
        if (jg < 32) {
            uint2 pk;
            pk.x = pk_fp8_4(clamp8(acc[0]), clamp8(acc[1]), clamp8(acc[2]), clamp8(acc[3]));
            pk.y = pk_fp8_4(clamp8(acc[4]), clamp8(acc[5]), clamp8(acc[6]), clamp8(acc[7]));
            out[jg] = pk;                 // A fp8: bytes [0,256)
        } else if (jg == 32) {
            a2 = f2bf_rne(acc[0]) | (f2bf_rne(acc[1]) << 16);   // k=256,257 of A
        } else if (jg < 65) {
            uint2 pk;
            pk.x = pk_fp8_4(clamp8(acc[0]), clamp8(acc[1]), clamp8(acc[2]), clamp8(acc[3]));
            pk.y = pk_fp8_4(clamp8(acc[4]), clamp8(acc[5]), clamp8(acc[6]), clamp8(acc[7]));
            out[jg - 1] = pk;             // B fp8: bytes [256,512)
        } else {
            b2 = f2bf_rne(acc[0]) | (f2bf_rne(acc[1]) << 16);   // k=256,257 of B
        }
    }
    uint32_t* pk = (uint32_t*)(pkt + (size_t)n * PKT_STRIDE);
    uint4 w0;
    w0.x = __float_as_uint(pos[3*n]);
    w0.y = __float_as_uint(pos[3*n+1]);
    w0.z = __float_as_uint(pos[3*n+2]);
    w0.w = a2;
    *(uint4*)pk = w0;
    pk[4] = b2;
}

// ---------------- per-edge fused message + coord + segmented scatter ----------------
__global__ void __launch_bounds__(256) edge_kernel(
        const uint2* __restrict__ sorted_st,
        const uint8_t* __restrict__ A8, const uint8_t* __restrict__ pkt,
        const float* __restrict__ We2, const float* __restrict__ be2,
        const float* __restrict__ Wc1, const float* __restrict__ bc1,
        const float* __restrict__ Wc2, const float* __restrict__ bc2,
        const float* __restrict__ w128,
        float* __restrict__ agg_msg, float* __restrict__ agg_pos, int E) {

    __shared__ __align__(16) vf2   We2p[KP2 * MDIM];   // [129][16] pair {W[2kp][m], W[2kp+1][m]}
    __shared__ __align__(16) vf2   w128p[KP2];
    __shared__ __align__(16) float Wc1s[MDIM * CHD];
    __shared__ __align__(16) float bc1s[CHD];
    __shared__ __align__(16) float Wc2s[CHD];
    __shared__ float be2s[MDIM];
    __shared__ float bc2s;

    // hoisted per-edge loads (overlap with staging)
    int e = blockIdx.x * 256 + threadIdx.x;
    bool active = (e < E);
    int ec = active ? e : (E - 1);
    uint2 st = sorted_st[ec];
    int s = (int)st.x;
    int tl = (int)st.y;                 // for loads
    int t = active ? tl : -1;           // for logic

    const uint4* pt = (const uint4*)(pkt + (size_t)tl * PKT_STRIDE);
    const uint4* ps = (const uint4*)(pkt + (size_t)s  * PKT_STRIDE);
    uint4 pt0 = pt[0];
    uint4 ps0 = ps[0];
    uint32_t b2 = ((const uint32_t*)ps)[4];
    uint32_t a2 = pt0.w;

    const uint4* ar = (const uint4*)(A8 + (size_t)tl * AB_STRIDE);        // A' (tgt), 256B
    const uint4* br = (const uint4*)(A8 + (size_t)s  * AB_STRIDE + 256);  // B  (src), 256B

    // stage weights to LDS
    for (int i = threadIdx.x; i < KP2 * MDIM; i += 256) {
        int kp = i >> 4, m = i & 15;
        int k0 = kp * 2;
        float lo = (k0     < EHD) ? We2[k0 * MDIM + m]       : 0.f;
        float hi = (k0 + 1 < EHD) ? We2[(k0 + 1) * MDIM + m] : 0.f;
        We2p[i] = (vf2){lo, hi};
    }
    for (int i = threadIdx.x; i < KP2; i += 256) {
        int k0 = i * 2;
        float lo = (k0     < EHD) ? w128[k0]     : 0.f;
        float hi = (k0 + 1 < EHD) ? w128[k0 + 1] : 0.f;
        w128p[i] = (vf2){lo, hi};
    }
    for (int i = threadIdx.x; i < MDIM * CHD; i += 256) Wc1s[i] = Wc1[i];
    if (threadIdx.x < CHD) { bc1s[threadIdx.x] = bc1[threadIdx.x]; Wc2s[threadIdx.x] = Wc2[threadIdx.x]; }
    if (threadIdx.x < MDIM) be2s[threadIdx.x] = be2[threadIdx.x];
    if (threadIdx.x == 0) bc2s = bc2[0];
    __syncthreads();

    float rx = __uint_as_float(pt0.x) - __uint_as_float(ps0.x);
    float ry = __uint_as_float(pt0.y) - __uint_as_float(ps0.y);
    float rz = __uint_as_float(pt0.z) - __uint_as_float(ps0.z);
    float d2 = rx*rx + ry*ry + rz*rz;
    vf2 d2v  = (vf2){d2, d2};
    vf2 invv = (vf2){FP8_INV, FP8_INV};

    vf2 macc[MDIM];
    #pragma unroll
    for (int m = 0; m < MDIM; ++m) macc[m] = (vf2){0.f, 0.f};

    #pragma unroll
    for (int kc = 0; kc < 16; ++kc) {
        uint4 a = ar[kc];
        uint4 b = br[kc];
        uint32_t au[4] = {a.x, a.y, a.z, a.w};
        uint32_t bu[4] = {b.x, b.y, b.z, b.w};
        #pragma unroll
        for (int q = 0; q < 4; ++q) {
            int kp = kc * 8 + q * 2;
            vf2 a01 = __builtin_amdgcn_cvt_pk_f32_fp8(au[q], false);
            vf2 a23 = __builtin_amdgcn_cvt_pk_f32_fp8(au[q], true);
            vf2 b01 = __builtin_amdgcn_cvt_pk_f32_fp8(bu[q], false);
            vf2 b23 = __builtin_amdgcn_cvt_pk_f32_fp8(bu[q], true);
            vf2 pre0 = (a01 + b01) * invv + d2v * w128p[kp];
            vf2 pre1 = (a23 + b23) * invv + d2v * w128p[kp + 1];
            vf2 h0, h1;
            h0.x = silu_f(pre0.x); h0.y = silu_f(pre0.y);
            h1.x = silu_f(pre1.x); h1.y = silu_f(pre1.y);
            const vf2* wr0 = &We2p[kp * MDIM];
            const vf2* wr1 = &We2p[(kp + 1) * MDIM];
            #pragma unroll
            for (int m = 0; m < MDIM; ++m) macc[m] += h0 * wr0[m];
            #pragma unroll
            for (int m = 0; m < MDIM; ++m) macc[m] += h1 * wr1[m];
        }
    }
    // extras pair k=256,257 (unscaled bf16 from packets)
    {
        vf2 ax = (vf2){bflo(a2), bfhi(a2)};
        vf2 bx = (vf2){bflo(b2), bfhi(b2)};
        vf2 pre = (ax + bx) + d2v * w128p[128];
        vf2 h;
        h.x = silu_f(pre.x); h.y = silu_f(pre.y);
        const vf2* wr = &We2p[128 * MDIM];
        #pragma unroll
        for (int m = 0; m < MDIM; ++m) macc[m] += h * wr[m];
    }

    float vals[19];
    vf2 msp[MDIM];
    #pragma unroll
    for (int m = 0; m < MDIM; ++m) {
        float v = silu_f(be2s[m] + macc[m].x + macc[m].y);
        vals[m] = v;
        msp[m] = (vf2){v, v};
    }

    // coord MLP, pair-packed over c
    const vf2* bc1v = (const vf2*)bc1s;
    const vf2* wc2v = (const vf2*)Wc2s;
    vf2 cwacc = (vf2){0.f, 0.f};
    #pragma unroll 4
    for (int cp = 0; cp < CHD / 2; ++cp) {
        vf2 tacc = bc1v[cp];
        #pragma unroll
        for (int m = 0; m < MDIM; ++m) {
            vf2 w = *(const vf2*)&Wc1s[m * CHD + 2 * cp];
            tacc += msp[m] * w;
        }
        vf2 hs;
        hs.x = silu_f(tacc.x);
        hs.y = silu_f(tacc.y);
        cwacc += hs * wc2v[cp];
    }
    float cw = bc2s + cwacc.x + cwacc.y;
    vals[16] = rx * cw;
    vals[17] = ry * cw;
    vals[18] = rz * cw;

    // wave-segmented inclusive scan over equal-t runs (edges sorted by t)
    int lane = threadIdx.x & 63;
    #pragma unroll
    for (int off = 1; off < 64; off <<= 1) {
        int tu = __shfl_up(t, off);
        bool same = (lane >= off) && (tu == t);
        #pragma unroll
        for (int v = 0; v < 19; ++v) {
            float vu = __shfl_up(vals[v], off);
            vals[v] += same ? vu : 0.f;
        }
    }
    int tn = __shfl_down(t, 1);
    bool last = (lane == 63) || (tn != t);
    if (active && last) {
        float* am = agg_msg + (size_t)t * MDIM;
        #pragma unroll
        for (int m = 0; m < MDIM; ++m) atomicAdd(&am[m], vals[m]);
        atomicAdd(&agg_pos[3*t],   vals[16]);
        atomicAdd(&agg_pos[3*t+1], vals[17]);
        atomicAdd(&agg_pos[3*t+2], vals[18]);
    }
}

// ---------------- per-node MLP + residual + pos update ----------------
__global__ void __launch_bounds__(256) node_kernel(
        float* __restrict__ x, float* __restrict__ pos,
        const float* __restrict__ agg_msg, const float* __restrict__ agg_pos,
        const float* __restrict__ Wn1t, const float* __restrict__ bn1,
        const float* __restrict__ Wn2, const float* __restrict__ bn2, int N) {
    int n = blockIdx.x * 256 + threadIdx.x;
    if (n >= N) return;
    float in[NIN];
    const float4* xp = (const float4*)(x + (size_t)n * NDIM);
    #pragma unroll
    for (int q = 0; q < 16; ++q) {
        float4 v = xp[q];
        in[4*q] = v.x; in[4*q+1] = v.y; in[4*q+2] = v.z; in[4*q+3] = v.w;
    }
    const float4* mp = (const float4*)(agg_msg + (size_t)n * MDIM);
    #pragma unroll
    for (int q = 0; q < 4; ++q) {
        float4 v = mp[q];
        in[64+4*q] = v.x; in[64+4*q+1] = v.y; in[64+4*q+2] = v.z; in[64+4*q+3] = v.w;
    }
    float out[NDIM];
    #pragma unroll
    for (int o = 0; o < NDIM; ++o) out[o] = bn2[o];
    for (int j = 0; j < NHD; ++j) {
        float t = bn1[j];
        const float4* w1 = (const float4*)(Wn1t + (size_t)j * NIN);
        #pragma unroll
        for (int q = 0; q < 20; ++q) {
            float4 w = w1[q];
            t += in[4*q]*w.x + in[4*q+1]*w.y + in[4*q+2]*w.z + in[4*q+3]*w.w;
        }
        float h = silu_f(t);
        const float4* w2 = (const float4*)(Wn2 + (size_t)j * NDIM);
        #pragma unroll
        for (int q = 0; q < 16; ++q) {
            float4 w = w2[q];
            out[4*q] += h*w.x; out[4*q+1] += h*w.y; out[4*q+2] += h*w.z; out[4*q+3] += h*w.w;
        }
    }
    float4* xo = (float4*)(x + (size_t)n * NDIM);
    #pragma unroll
    for (int q = 0; q < 16; ++q) {
        float4 v;
        v.x = in[4*q]   + out[4*q];
        v.y = in[4*q+1] + out[4*q+1];
        v.z = in[4*q+2] + out[4*q+2];
        v.w = in[4*q+3] + out[4*q+3];
        xo[q] = v;
    }
    pos[3*n]   += agg_pos[3*n];
    pos[3*n+1] += agg_pos[3*n+1];
    pos[3*n+2] += agg_pos[3*n+2];
}

// ---------------- host launch ----------------
extern "C" void kernel_launch(void* const* d_in, const int* in_sizes, int n_in,
                              void* d_out, int out_size, void* d_ws, size_t ws_size,
                              hipStream_t stream) {
    const int*   feats = (const int*)  d_in[0];
    const float* coors = (const float*)d_in[1];
    const int*   ei    = (const int*)  d_in[2];
    const float* emb   = (const float*)d_in[3];
    const float* We1   = (const float*)d_in[4];
    const float* be1   = (const float*)d_in[5];
    const float* We2   = (const float*)d_in[6];
    const float* be2   = (const float*)d_in[7];
    const float* Wc1   = (const float*)d_in[8];
    const float* bc1   = (const float*)d_in[9];
    const float* Wc2   = (const float*)d_in[10];
    const float* bc2   = (const float*)d_in[11];
    const float* Wn1   = (const float*)d_in[12];
    const float* bn1   = (const float*)d_in[13];
    const float* Wn2   = (const float*)d_in[14];
    const float* bn2   = (const float*)d_in[15];

    const int N = in_sizes[0];
    const int E = in_sizes[2] / 2;

    float* x   = (float*)d_out;                     // [N,64]
    float* pos = (float*)d_out + (size_t)N * NDIM;  // [N,3]

    // workspace layout (256B aligned chunks). pkt MUST follow A8 (over-read safety).
    char* w = (char*)d_ws;
    uint8_t* A8 = (uint8_t*)w;                                  // N*512
    size_t off = ((size_t)N * AB_STRIDE + 255) & ~(size_t)255;
    uint8_t* pkt = (uint8_t*)(w + off);                         // N*32
    off += ((size_t)N * PKT_STRIDE + 255) & ~(size_t)255;
    float* agg_msg = (float*)(w + off);                         // N*16
    off += ((size_t)N * MDIM * 4 + 255) & ~(size_t)255;
    float* agg_pos = (float*)(w + off);                         // N*3
    off += ((size_t)N * 3 * 4 + 255) & ~(size_t)255;
    uint2* sorted_st = (uint2*)(w + off);                       // E*8
    off += ((size_t)E * 8 + 255) & ~(size_t)255;
    int* cnt = (int*)(w + off);                                 // N
    off += ((size_t)N * 4 + 255) & ~(size_t)255;
    int* cursor = (int*)(w + off);                              // N
    off += ((size_t)N * 4 + 255) & ~(size_t)255;
    float* Wtg = (float*)(w + off);                             // 3*33792
    off += (size_t)NLAYER * 33792 * 4;
    float* biasAB = (float*)(w + off);                          // 3*528
    off += (size_t)NLAYER * 528 * 4;
    float* Wn1t = (float*)(w + off);                            // 3*128*80
    (void)ws_size; (void)n_in; (void)out_size;

    {
        int total = NLAYER * 33792 + NLAYER * 528 + NLAYER * NHD * NIN;
        prep_kernel<<<(total + 255) / 256, 256, 0, stream>>>(We1, be1, Wn1, Wtg, biasAB, Wn1t);
    }
    {
        int total = N * (NDIM + 3);
        init_kernel<<<(total + 255) / 256, 256, 0, stream>>>(feats, coors, emb, x, pos, N);
    }
    // counting sort by target (once; edge_index constant across layers)
    hipMemsetAsync(cnt, 0, (size_t)N * 4, stream);
    hist_kernel<<<(E + 255) / 256, 256, 0, stream>>>(ei, cnt, E);
    scan_kernel<<<1, 1024, 0, stream>>>(cnt, cursor, N);
    scatter_kernel<<<(E + 255) / 256, 256, 0, stream>>>(ei, cursor, sorted_st, E);

    for (int l = 0; l < NLAYER; ++l) {
        const float* We1_l  = We1 + (size_t)l * EIN * EHD;
        const float* w128_l = We1_l + (size_t)128 * EHD;

        gemm_ab_kernel<<<(N + 255) / 256, 256, 0, stream>>>(
            x, pos, Wtg + (size_t)l * 33792, biasAB + (size_t)l * 528, A8, pkt, N);

        hipMemsetAsync(agg_msg, 0, (size_t)N * MDIM * 4, stream);
        hipMemsetAsync(agg_pos, 0, (size_t)N * 3 * 4, stream);

        edge_kernel<<<(E + 255) / 256, 256, 0, stream>>>(
            sorted_st, A8, pkt,
            We2 + (size_t)l * EHD * MDIM, be2 + (size_t)l * MDIM,
            Wc1 + (size_t)l * MDIM * CHD, bc1 + (size_t)l * CHD,
            Wc2 + (size_t)l * CHD, bc2 + l, w128_l,
            agg_msg, agg_pos, E);

        node_kernel<<<(N + 255) / 256, 256, 0, stream>>>(
            x, pos, agg_msg, agg_pos,
            Wn1t + (size_t)l * NHD * NIN, bn1 + (size_t)l * NHD,
            Wn2 + (size_t)l * NHD * NDIM, bn2 + (size_t)l * NDIM, N);
    }
}

// Round 4
// 1586.199 us; speedup vs baseline: 4.6809x; 1.6525x over previous
//
#include <hip/hip_runtime.h>
#include <hip/hip_bf16.h>
#include <stdint.h>

#define NDIM   64     // node channels D
#define MDIM   16     // msg channels
#define NLAYER 3
#define EIN    129    // 2D+1
#define EHD    258    // edge hidden
#define CHD    64     // coord hidden
#define NHD    128    // node hidden
#define NIN    80     // D + M
#define KP2    129    // packed k-pairs: 128 fp8 pairs + 1 extras pair
#define AB_STRIDE 512 // bytes per node in fp8 AB table (A 256B | B 256B)
#define PKT_STRIDE 32 // bytes per node packet: pos xyz f32, a2 bf16x2, b2 bf16x2
#define FP8_SCALE 1024.0f
#define FP8_INV   (1.0f/1024.0f)

// fragment-table element counts (per layer, in bf16 elems)
#define WE1F_L (34*2*512)   // 34816
#define WN1F_L (8*3*512)    // 12288
#define WN2F_L (4*4*512)    // 8192

typedef float vf2 __attribute__((ext_vector_type(2)));
typedef __bf16 bf16x8 __attribute__((ext_vector_type(8)));
typedef float  f32x4  __attribute__((ext_vector_type(4)));

#define MFMA16(a, b, c) __builtin_amdgcn_mfma_f32_16x16x32_bf16((a), (b), (c), 0, 0, 0)

__device__ __forceinline__ float rcp_f(float x) { return __builtin_amdgcn_rcpf(x); }
__device__ __forceinline__ float silu_f(float v) {
    return v * rcp_f(1.0f + __expf(-v));
}
__device__ __forceinline__ float bflo(uint32_t u) {
    union { uint32_t u; float f; } c; c.u = u << 16; return c.f;
}
__device__ __forceinline__ float bfhi(uint32_t u) {
    union { uint32_t u; float f; } c; c.u = u & 0xffff0000u; return c.f;
}
__device__ __forceinline__ uint32_t pk_fp8_4(float f0, float f1, float f2, float f3) {
    uint32_t r = (uint32_t)__builtin_amdgcn_cvt_pk_fp8_f32(f0, f1, 0, false);
    r = (uint32_t)__builtin_amdgcn_cvt_pk_fp8_f32(f2, f3, (int)r, true);
    return r;
}
__device__ __forceinline__ float clamp8(float v) {
    return fminf(448.0f, fmaxf(-448.0f, v * FP8_SCALE));
}

// ---------------- prep: weights -> MFMA B-fragment order (bf16) ----------------
// Fragment layout rule (mfma_f32_16x16x32_bf16 B operand):
//   lane holds B[k = kh*32 + (lane>>4)*8 + jj][col = ct*16 + (lane&15)]
// WE1F: [l][ct(34: 0-16 A-half, 17-33 B-half)][kh(2)][lane(64)][jj(8)]
//   A-half col c -> We1[l][k][c] (c<258), B-half -> We1[l][64+k][c]
// WN1F: [l][ct(8)][kt(3)][lane][jj]; k<80 from Wn1, else 0
// WN2F: [l][ct(4)][kt(4)][lane][jj]
__global__ void prep_kernel(const float* __restrict__ We1, const float* __restrict__ Wn1,
                            const float* __restrict__ Wn2,
                            __bf16* __restrict__ WE1F, __bf16* __restrict__ WN1F,
                            __bf16* __restrict__ WN2F) {
    int idx = blockIdx.x * 256 + threadIdx.x;
    const int T1 = NLAYER * WE1F_L;
    if (idx < T1) {
        int l  = idx / WE1F_L;
        int r  = idx % WE1F_L;
        int ct = r / 1024;
        int r2 = r % 1024;
        int kh = r2 / 512;
        int r3 = r2 % 512;
        int lane = r3 >> 3, jj = r3 & 7;
        int half = ct / 17, ctl = ct % 17;
        int col = ctl * 16 + (lane & 15);
        int k = kh * 32 + (lane >> 4) * 8 + jj;
        float v = 0.f;
        if (col < EHD) v = We1[((size_t)l * EIN + (half ? 64 + k : k)) * EHD + col];
        WE1F[idx] = (__bf16)v;
        return;
    }
    idx -= T1;
    const int T2 = NLAYER * WN1F_L;
    if (idx < T2) {
        int l  = idx / WN1F_L;
        int r  = idx % WN1F_L;
        int ct = r / 1536;
        int r2 = r % 1536;
        int kt = r2 / 512;
        int r3 = r2 % 512;
        int lane = r3 >> 3, jj = r3 & 7;
        int col = ct * 16 + (lane & 15);
        int k = kt * 32 + (lane >> 4) * 8 + jj;
        float v = (k < NIN) ? Wn1[((size_t)l * NIN + k) * NHD + col] : 0.f;
        WN1F[idx] = (__bf16)v;
        return;
    }
    idx -= T2;
    const int T3 = NLAYER * WN2F_L;
    if (idx < T3) {
        int l  = idx / WN2F_L;
        int r  = idx % WN2F_L;
        int ct = r / 2048;
        int r2 = r % 2048;
        int kt = r2 / 512;
        int r3 = r2 % 512;
        int lane = r3 >> 3, jj = r3 & 7;
        int col = ct * 16 + (lane & 15);
        int k = kt * 32 + (lane >> 4) * 8 + jj;
        WN2F[idx] = (__bf16)Wn2[((size_t)l * NHD + k) * NDIM + col];
    }
}

// ---------------- init: embedding lookup + pos copy ----------------
__global__ void init_kernel(const int* __restrict__ feats, const float* __restrict__ coors,
                            const float* __restrict__ emb,
                            float* __restrict__ x, float* __restrict__ pos, int N) {
    int idx = blockIdx.x * 256 + threadIdx.x;
    int nx = N * NDIM;
    if (idx < nx) {
        int n = idx >> 6, c = idx & 63;
        x[idx] = emb[feats[n] * NDIM + c];
    } else {
        int j = idx - nx;
        if (j < N * 3) pos[j] = coors[j];
    }
}

// ---------------- counting sort by target ----------------
__global__ void hist_kernel(const int* __restrict__ ei, int* __restrict__ cnt, int E) {
    int e = blockIdx.x * 256 + threadIdx.x;
    if (e < E) atomicAdd(&cnt[ei[E + e]], 1);
}

__global__ void __launch_bounds__(1024) scan_kernel(const int* __restrict__ cnt,
                                                    int* __restrict__ cursor, int N) {
    __shared__ int wsum[16];
    __shared__ int carry_s;
    int tid = threadIdx.x, lane = tid & 63, w = tid >> 6;
    if (tid == 0) carry_s = 0;
    __syncthreads();
    for (int base = 0; base < N; base += 1024) {
        int i = base + tid;
        int v = (i < N) ? cnt[i] : 0;
        int sc = v;
        #pragma unroll
        for (int off = 1; off < 64; off <<= 1) {
            int u = __shfl_up(sc, off);
            if (lane >= off) sc += u;
        }
        if (lane == 63) wsum[w] = sc;
        __syncthreads();
        int woff = 0;
        #pragma unroll
        for (int k = 0; k < 16; ++k) woff += (k < w) ? wsum[k] : 0;
        int carry = carry_s;
        if (i < N) cursor[i] = carry + woff + sc - v;
        __syncthreads();
        if (tid == 1023) carry_s = carry + woff + sc;
        __syncthreads();
    }
}

__global__ void scatter_kernel(const int* __restrict__ ei, int* __restrict__ cursor,
                               uint2* __restrict__ sorted_st, int E) {
    int e = blockIdx.x * 256 + threadIdx.x;
    if (e >= E) return;
    int s = ei[e], t = ei[E + e];
    int p = atomicAdd(&cursor[t], 1);
    uint2 st; st.x = (uint32_t)s; st.y = (uint32_t)t;
    sorted_st[p] = st;
}

// ---------------- MFMA: AB table build. wave = (node16, half) -----------------
// wave computes C[16 nodes][272 cols-of-its-half] = x_bf16 @ We1_half (+be1 if A)
__global__ void __launch_bounds__(256) gemm_ab_mfma(
        const float* __restrict__ x, const float* __restrict__ pos,
        const bf16x8* __restrict__ WE1Fl, const float* __restrict__ be1l,
        uint8_t* __restrict__ A8, uint8_t* __restrict__ pkt, int N) {
    __shared__ __align__(16) __bf16 stg[4][16][280];   // 280 u16 row stride (bank spread)
    int wave = threadIdx.x >> 6, lane = threadIdx.x & 63;
    int half = wave & 1;
    int nb = blockIdx.x * 32 + (wave >> 1) * 16;
    int lrow = lane & 15, lkg = lane >> 4;
    int row = nb + lrow; if (row >= N) row = N - 1;

    const float* xr = x + (size_t)row * NDIM + lkg * 8;
    bf16x8 a0, a1;
    #pragma unroll
    for (int j = 0; j < 8; ++j) { a0[j] = (__bf16)xr[j]; a1[j] = (__bf16)xr[32 + j]; }

    f32x4 acc[17];
    #pragma unroll
    for (int t = 0; t < 17; ++t) acc[t] = (f32x4){0.f, 0.f, 0.f, 0.f};
    const bf16x8* bf = WE1Fl + (size_t)(half * 17) * 2 * 64 + lane;
    #pragma unroll
    for (int t = 0; t < 17; ++t) {
        bf16x8 b0 = bf[(t * 2 + 0) * 64];
        bf16x8 b1 = bf[(t * 2 + 1) * 64];
        acc[t] = MFMA16(a0, b0, acc[t]);
        acc[t] = MFMA16(a1, b1, acc[t]);
    }
    // stage to LDS (bias added here; C/D layout: col=lane&15, row=(lane>>4)*4+r)
    #pragma unroll
    for (int t = 0; t < 17; ++t) {
        int col = t * 16 + lrow;
        float bias = (half == 0 && col < EHD) ? be1l[col] : 0.f;
        #pragma unroll
        for (int r = 0; r < 4; ++r)
            stg[wave][lkg * 4 + r][col] = (__bf16)(acc[t][r] + bias);
    }
    __syncthreads();

    // pack fp8: lane -> node = lane>>2, 64-col chunk = (lane&3)*64
    int node = lane >> 2;
    int gnode = nb + node;
    const __bf16* hrow = &stg[wave][node][(lane & 3) * 64];
    if (gnode < N) {
        uint8_t* dst = A8 + (size_t)gnode * AB_STRIDE + half * 256 + (lane & 3) * 64;
        #pragma unroll
        for (int g = 0; g < 8; ++g) {
            bf16x8 hv = *(const bf16x8*)(hrow + g * 8);
            uint2 pk;
            pk.x = pk_fp8_4(clamp8((float)hv[0]), clamp8((float)hv[1]),
                            clamp8((float)hv[2]), clamp8((float)hv[3]));
            pk.y = pk_fp8_4(clamp8((float)hv[4]), clamp8((float)hv[5]),
                            clamp8((float)hv[6]), clamp8((float)hv[7]));
            *(uint2*)(dst + g * 8) = pk;
        }
    }
    // extras (cols 256,257 bf16) + pos packet
    if (lane < 16 && nb + lane < N) {
        int gn = nb + lane;
        const uint16_t* hr = (const uint16_t*)&stg[wave][lane][256];
        uint32_t ex = (uint32_t)hr[0] | ((uint32_t)hr[1] << 16);
        uint32_t* pk = (uint32_t*)(pkt + (size_t)gn * PKT_STRIDE);
        if (half == 0) {
            uint4 w0;
            w0.x = __float_as_uint(pos[3 * gn]);
            w0.y = __float_as_uint(pos[3 * gn + 1]);
            w0.z = __float_as_uint(pos[3 * gn + 2]);
            w0.w = ex;
            *(uint4*)pk = w0;
        } else {
            pk[4] = ex;
        }
    }
}

// ---------------- per-edge fused message + coord + segmented scatter ----------------
__global__ void __launch_bounds__(256) edge_kernel(
        const uint2* __restrict__ sorted_st,
        const uint8_t* __restrict__ A8, const uint8_t* __restrict__ pkt,
        const float* __restrict__ We2, const float* __restrict__ be2,
        const float* __restrict__ Wc1, const float* __restrict__ bc1,
        const float* __restrict__ Wc2, const float* __restrict__ bc2,
        const float* __restrict__ w128,
        float* __restrict__ agg_msg, float* __restrict__ agg_pos, int E) {

    __shared__ __align__(16) vf2   We2p[KP2 * MDIM];
    __shared__ __align__(16) vf2   w128p[KP2];
    __shared__ __align__(16) float Wc1s[MDIM * CHD];
    __shared__ __align__(16) float bc1s[CHD];
    __shared__ __align__(16) float Wc2s[CHD];
    __shared__ float be2s[MDIM];
    __shared__ float bc2s;

    int e = blockIdx.x * 256 + threadIdx.x;
    bool active = (e < E);
    int ec = active ? e : (E - 1);
    uint2 st = sorted_st[ec];
    int s = (int)st.x;
    int tl = (int)st.y;
    int t = active ? tl : -1;

    const uint4* pt = (const uint4*)(pkt + (size_t)tl * PKT_STRIDE);
    const uint4* ps = (const uint4*)(pkt + (size_t)s  * PKT_STRIDE);
    uint4 pt0 = pt[0];
    uint4 ps0 = ps[0];
    uint32_t b2 = ((const uint32_t*)ps)[4];
    uint32_t a2 = pt0.w;

    const uint4* ar = (const uint4*)(A8 + (size_t)tl * AB_STRIDE);
    const uint4* br = (const uint4*)(A8 + (size_t)s  * AB_STRIDE + 256);

    for (int i = threadIdx.x; i < KP2 * MDIM; i += 256) {
        int kp = i >> 4, m = i & 15;
        int k0 = kp * 2;
        float lo = (k0     < EHD) ? We2[k0 * MDIM + m]       : 0.f;
        float hi = (k0 + 1 < EHD) ? We2[(k0 + 1) * MDIM + m] : 0.f;
        We2p[i] = (vf2){lo, hi};
    }
    for (int i = threadIdx.x; i < KP2; i += 256) {
        int k0 = i * 2;
        float lo = (k0     < EHD) ? w128[k0]     : 0.f;
        float hi = (k0 + 1 < EHD) ? w128[k0 + 1] : 0.f;
        w128p[i] = (vf2){lo, hi};
    }
    for (int i = threadIdx.x; i < MDIM * CHD; i += 256) Wc1s[i] = Wc1[i];
    if (threadIdx.x < CHD) { bc1s[threadIdx.x] = bc1[threadIdx.x]; Wc2s[threadIdx.x] = Wc2[threadIdx.x]; }
    if (threadIdx.x < MDIM) be2s[threadIdx.x] = be2[threadIdx.x];
    if (threadIdx.x == 0) bc2s = bc2[0];
    __syncthreads();

    float rx = __uint_as_float(pt0.x) - __uint_as_float(ps0.x);
    float ry = __uint_as_float(pt0.y) - __uint_as_float(ps0.y);
    float rz = __uint_as_float(pt0.z) - __uint_as_float(ps0.z);
    float d2 = rx*rx + ry*ry + rz*rz;
    vf2 d2v  = (vf2){d2, d2};
    vf2 invv = (vf2){FP8_INV, FP8_INV};

    vf2 macc[MDIM];
    #pragma unroll
    for (int m = 0; m < MDIM; ++m) macc[m] = (vf2){0.f, 0.f};

    #pragma unroll
    for (int kc = 0; kc < 16; ++kc) {
        uint4 a = ar[kc];
        uint4 b = br[kc];
        uint32_t au[4] = {a.x, a.y, a.z, a.w};
        uint32_t bu[4] = {b.x, b.y, b.z, b.w};
        #pragma unroll
        for (int q = 0; q < 4; ++q) {
            int kp = kc * 8 + q * 2;
            vf2 a01 = __builtin_amdgcn_cvt_pk_f32_fp8(au[q], false);
            vf2 a23 = __builtin_amdgcn_cvt_pk_f32_fp8(au[q], true);
            vf2 b01 = __builtin_amdgcn_cvt_pk_f32_fp8(bu[q], false);
            vf2 b23 = __builtin_amdgcn_cvt_pk_f32_fp8(bu[q], true);
            vf2 pre0 = (a01 + b01) * invv + d2v * w128p[kp];
            vf2 pre1 = (a23 + b23) * invv + d2v * w128p[kp + 1];
            vf2 h0, h1;
            h0.x = silu_f(pre0.x); h0.y = silu_f(pre0.y);
            h1.x = silu_f(pre1.x); h1.y = silu_f(pre1.y);
            const vf2* wr0 = &We2p[kp * MDIM];
            const vf2* wr1 = &We2p[(kp + 1) * MDIM];
            #pragma unroll
            for (int m = 0; m < MDIM; ++m) macc[m] += h0 * wr0[m];
            #pragma unroll
            for (int m = 0; m < MDIM; ++m) macc[m] += h1 * wr1[m];
        }
    }
    {
        vf2 ax = (vf2){bflo(a2), bfhi(a2)};
        vf2 bx = (vf2){bflo(b2), bfhi(b2)};
        vf2 pre = (ax + bx) + d2v * w128p[128];
        vf2 h;
        h.x = silu_f(pre.x); h.y = silu_f(pre.y);
        const vf2* wr = &We2p[128 * MDIM];
        #pragma unroll
        for (int m = 0; m < MDIM; ++m) macc[m] += h * wr[m];
    }

    float vals[19];
    vf2 msp[MDIM];
    #pragma unroll
    for (int m = 0; m < MDIM; ++m) {
        float v = silu_f(be2s[m] + macc[m].x + macc[m].y);
        vals[m] = v;
        msp[m] = (vf2){v, v};
    }

    const vf2* bc1v = (const vf2*)bc1s;
    const vf2* wc2v = (const vf2*)Wc2s;
    vf2 cwacc = (vf2){0.f, 0.f};
    #pragma unroll 4
    for (int cp = 0; cp < CHD / 2; ++cp) {
        vf2 tacc = bc1v[cp];
        #pragma unroll
        for (int m = 0; m < MDIM; ++m) {
            vf2 w = *(const vf2*)&Wc1s[m * CHD + 2 * cp];
            tacc += msp[m] * w;
        }
        vf2 hs;
        hs.x = silu_f(tacc.x);
        hs.y = silu_f(tacc.y);
        cwacc += hs * wc2v[cp];
    }
    float cw = bc2s + cwacc.x + cwacc.y;
    vals[16] = rx * cw;
    vals[17] = ry * cw;
    vals[18] = rz * cw;

    int lane = threadIdx.x & 63;
    #pragma unroll
    for (int off = 1; off < 64; off <<= 1) {
        int tu = __shfl_up(t, off);
        bool same = (lane >= off) && (tu == t);
        #pragma unroll
        for (int v = 0; v < 19; ++v) {
            float vu = __shfl_up(vals[v], off);
            vals[v] += same ? vu : 0.f;
        }
    }
    int tn = __shfl_down(t, 1);
    bool last = (lane == 63) || (tn != t);
    if (active && last) {
        float* am = agg_msg + (size_t)t * MDIM;
        #pragma unroll
        for (int m = 0; m < MDIM; ++m) atomicAdd(&am[m], vals[m]);
        atomicAdd(&agg_pos[3*t],   vals[16]);
        atomicAdd(&agg_pos[3*t+1], vals[17]);
        atomicAdd(&agg_pos[3*t+2], vals[18]);
    }
}

// ---------------- MFMA node MLP + residual + pos update ----------------
__global__ void __launch_bounds__(256) node_mfma(
        float* __restrict__ x, float* __restrict__ pos,
        const float* __restrict__ agg_msg, const float* __restrict__ agg_pos,
        const bf16x8* __restrict__ WN1Fl, const bf16x8* __restrict__ WN2Fl,
        const float* __restrict__ bn1l, const float* __restrict__ bn2l, int N) {
    __shared__ __align__(16) __bf16 stg[4][16][136];
    int wave = threadIdx.x >> 6, lane = threadIdx.x & 63;
    int nb = blockIdx.x * 64 + wave * 16;
    int lrow = lane & 15, lkg = lane >> 4;
    int row = nb + lrow;
    int rc = (row < N) ? row : (N - 1);

    const float* xr = x + (size_t)rc * NDIM + lkg * 8;
    bf16x8 a0, a1, a2;
    #pragma unroll
    for (int j = 0; j < 8; ++j) { a0[j] = (__bf16)xr[j]; a1[j] = (__bf16)xr[32 + j]; }
    if (lkg < 2) {
        const float* mr = agg_msg + (size_t)rc * MDIM + lkg * 8;
        #pragma unroll
        for (int j = 0; j < 8; ++j) a2[j] = (__bf16)mr[j];
    } else {
        #pragma unroll
        for (int j = 0; j < 8; ++j) a2[j] = (__bf16)0.f;
    }

    f32x4 h[8];
    #pragma unroll
    for (int t = 0; t < 8; ++t) h[t] = (f32x4){0.f, 0.f, 0.f, 0.f};
    const bf16x8* b1 = WN1Fl + lane;
    #pragma unroll
    for (int t = 0; t < 8; ++t) {
        h[t] = MFMA16(a0, b1[(t * 3 + 0) * 64], h[t]);
        h[t] = MFMA16(a1, b1[(t * 3 + 1) * 64], h[t]);
        h[t] = MFMA16(a2, b1[(t * 3 + 2) * 64], h[t]);
    }
    #pragma unroll
    for (int t = 0; t < 8; ++t) {
        int col = t * 16 + lrow;
        float bias = bn1l[col];
        #pragma unroll
        for (int r = 0; r < 4; ++r)
            stg[wave][lkg * 4 + r][col] = (__bf16)silu_f(h[t][r] + bias);
    }
    __syncthreads();

    bf16x8 af[4];
    #pragma unroll
    for (int kt = 0; kt < 4; ++kt)
        af[kt] = *(const bf16x8*)&stg[wave][lrow][kt * 32 + lkg * 8];

    f32x4 o[4];
    #pragma unroll
    for (int t = 0; t < 4; ++t) o[t] = (f32x4){0.f, 0.f, 0.f, 0.f};
    const bf16x8* b2 = WN2Fl + lane;
    #pragma unroll
    for (int t = 0; t < 4; ++t) {
        #pragma unroll
        for (int kt = 0; kt < 4; ++kt)
            o[t] = MFMA16(af[kt], b2[(t * 4 + kt) * 64], o[t]);
    }

    int orow = nb + lkg * 4;
    #pragma unroll
    for (int t = 0; t < 4; ++t) {
        int col = t * 16 + lrow;
        float bias = bn2l[col];
        #pragma unroll
        for (int r = 0; r < 4; ++r) {
            int rr = orow + r;
            if (rr < N) x[(size_t)rr * NDIM + col] += o[t][r] + bias;
        }
    }
    // pos update (64 nodes * 3 floats per block)
    if (threadIdx.x < 192) {
        long j = (long)blockIdx.x * 192 + threadIdx.x;
        if (j < (long)N * 3) pos[j] += agg_pos[j];
    }
}

// ---------------- host launch ----------------
extern "C" void kernel_launch(void* const* d_in, const int* in_sizes, int n_in,
                              void* d_out, int out_size, void* d_ws, size_t ws_size,
                              hipStream_t stream) {
    const int*   feats = (const int*)  d_in[0];
    const float* coors = (const float*)d_in[1];
    const int*   ei    = (const int*)  d_in[2];
    const float* emb   = (const float*)d_in[3];
    const float* We1   = (const float*)d_in[4];
    const float* be1   = (const float*)d_in[5];
    const float* We2   = (const float*)d_in[6];
    const float* be2   = (const float*)d_in[7];
    const float* Wc1   = (const float*)d_in[8];
    const float* bc1   = (const float*)d_in[9];
    const float* Wc2   = (const float*)d_in[10];
    const float* bc2   = (const float*)d_in[11];
    const float* Wn1   = (const float*)d_in[12];
    const float* bn1   = (const float*)d_in[13];
    const float* Wn2   = (const float*)d_in[14];
    const float* bn2   = (const float*)d_in[15];

    const int N = in_sizes[0];
    const int E = in_sizes[2] / 2;

    float* x   = (float*)d_out;                     // [N,64]
    float* pos = (float*)d_out + (size_t)N * NDIM;  // [N,3]

    // workspace layout
    char* w = (char*)d_ws;
    uint8_t* A8 = (uint8_t*)w;                                  // N*512
    size_t off = ((size_t)N * AB_STRIDE + 255) & ~(size_t)255;
    uint8_t* pkt = (uint8_t*)(w + off);                         // N*32
    off += ((size_t)N * PKT_STRIDE + 255) & ~(size_t)255;
    float* agg_msg = (float*)(w + off);                         // N*16
    off += ((size_t)N * MDIM * 4 + 255) & ~(size_t)255;
    float* agg_pos = (float*)(w + off);                         // N*3
    off += ((size_t)N * 3 * 4 + 255) & ~(size_t)255;
    uint2* sorted_st = (uint2*)(w + off);                       // E*8
    off += ((size_t)E * 8 + 255) & ~(size_t)255;
    int* cnt = (int*)(w + off);                                 // N
    off += ((size_t)N * 4 + 255) & ~(size_t)255;
    int* cursor = (int*)(w + off);                              // N
    off += ((size_t)N * 4 + 255) & ~(size_t)255;
    __bf16* WE1F = (__bf16*)(w + off);                          // 3*34816 bf16
    off += ((size_t)NLAYER * WE1F_L * 2 + 255) & ~(size_t)255;
    __bf16* WN1F = (__bf16*)(w + off);                          // 3*12288
    off += ((size_t)NLAYER * WN1F_L * 2 + 255) & ~(size_t)255;
    __bf16* WN2F = (__bf16*)(w + off);                          // 3*8192
    (void)ws_size; (void)n_in; (void)out_size;

    {
        int total = NLAYER * (WE1F_L + WN1F_L + WN2F_L);
        prep_kernel<<<(total + 255) / 256, 256, 0, stream>>>(We1, Wn1, Wn2, WE1F, WN1F, WN2F);
    }
    {
        int total = N * (NDIM + 3);
        init_kernel<<<(total + 255) / 256, 256, 0, stream>>>(feats, coors, emb, x, pos, N);
    }
    // counting sort by target (once; edge_index constant across layers)
    hipMemsetAsync(cnt, 0, (size_t)N * 4, stream);
    hist_kernel<<<(E + 255) / 256, 256, 0, stream>>>(ei, cnt, E);
    scan_kernel<<<1, 1024, 0, stream>>>(cnt, cursor, N);
    scatter_kernel<<<(E + 255) / 256, 256, 0, stream>>>(ei, cursor, sorted_st, E);

    for (int l = 0; l < NLAYER; ++l) {
        const float* We1_l  = We1 + (size_t)l * EIN * EHD;
        const float* w128_l = We1_l + (size_t)128 * EHD;

        gemm_ab_mfma<<<(N + 31) / 32, 256, 0, stream>>>(
            x, pos, (const bf16x8*)(WE1F + (size_t)l * WE1F_L),
            be1 + (size_t)l * EHD, A8, pkt, N);

        hipMemsetAsync(agg_msg, 0, (size_t)N * MDIM * 4, stream);
        hipMemsetAsync(agg_pos, 0, (size_t)N * 3 * 4, stream);

        edge_kernel<<<(E + 255) / 256, 256, 0, stream>>>(
            sorted_st, A8, pkt,
            We2 + (size_t)l * EHD * MDIM, be2 + (size_t)l * MDIM,
            Wc1 + (size_t)l * MDIM * CHD, bc1 + (size_t)l * CHD,
            Wc2 + (size_t)l * CHD, bc2 + l, w128_l,
            agg_msg, agg_pos, E);

        node_mfma<<<(N + 63) / 64, 256, 0, stream>>>(
            x, pos, agg_msg, agg_pos,
            (const bf16x8*)(WN1F + (size_t)l * WN1F_L),
            (const bf16x8*)(WN2F + (size_t)l * WN2F_L),
            bn1 + (size_t)l * NHD, bn2 + (size_t)l * NDIM, N);
    }
}

// Round 5
// 1243.489 us; speedup vs baseline: 5.9709x; 1.2756x over previous
//
#include <hip/hip_runtime.h>
#include <hip/hip_bf16.h>
#include <stdint.h>

#define NDIM   64     // node channels D
#define MDIM   16     // msg channels
#define NLAYER 3
#define EIN    129    // 2D+1
#define EHD    258    // edge hidden
#define CHD    64     // coord hidden
#define NHD    128    // node hidden
#define NIN    80     // D + M
#define AB_STRIDE 512 // bytes per node in fp8 AB table (A 256B | B 256B)
#define PKT_STRIDE 32 // bytes per node packet: pos xyz f32, a2 bf16x2, b2 bf16x2
#define FP8_SCALE 1024.0f

// fragment-table element counts (per layer, in bf16 elems)
#define WE1F_L (34*2*512)   // 34816
#define WN1F_L (8*3*512)    // 12288
#define WN2F_L (4*4*512)    // 8192
#define WE2F_L (9*512)      // 4608: [kt(9)][lane(64)][jj(8)] = We2[k][m]/1024

typedef float vf2 __attribute__((ext_vector_type(2)));
typedef __bf16 bf16x8 __attribute__((ext_vector_type(8)));
typedef float  f32x4  __attribute__((ext_vector_type(4)));

#define MFMA16(a, b, c) __builtin_amdgcn_mfma_f32_16x16x32_bf16((a), (b), (c), 0, 0, 0)

__device__ __forceinline__ float rcp_f(float x) { return __builtin_amdgcn_rcpf(x); }
#if __has_builtin(__builtin_amdgcn_exp2f)
__device__ __forceinline__ float exp2_f(float x) { return __builtin_amdgcn_exp2f(x); }
#else
__device__ __forceinline__ float exp2_f(float x) { return __expf(x * 0.6931471805599453f); }
#endif
__device__ __forceinline__ float silu_f(float v) {
    return v * rcp_f(1.0f + __expf(-v));
}
// h' = u * sigmoid(u/1024)  (u = 1024*pre_h); CC = -log2(e)/1024
#define CC_EXP (-1.4426950408889634f / 1024.0f)
__device__ __forceinline__ float hprime_f(float u) {
    return u * rcp_f(1.0f + exp2_f(CC_EXP * u));
}
__device__ __forceinline__ float bflo(uint32_t u) {
    union { uint32_t u; float f; } c; c.u = u << 16; return c.f;
}
__device__ __forceinline__ float bfhi(uint32_t u) {
    union { uint32_t u; float f; } c; c.u = u & 0xffff0000u; return c.f;
}
__device__ __forceinline__ uint32_t pk_fp8_4(float f0, float f1, float f2, float f3) {
    uint32_t r = (uint32_t)__builtin_amdgcn_cvt_pk_fp8_f32(f0, f1, 0, false);
    r = (uint32_t)__builtin_amdgcn_cvt_pk_fp8_f32(f2, f3, (int)r, true);
    return r;
}
__device__ __forceinline__ float clamp8(float v) {
    return fminf(448.0f, fmaxf(-448.0f, v * FP8_SCALE));
}

// ---------------- prep: weights -> MFMA fragment order (bf16) ----------------
// B-frag rule (mfma_f32_16x16x32_bf16): lane holds B[k=(lane>>4)*8+jj + 32*kt][col=ct*16+(lane&15)]
__global__ void prep_kernel(const float* __restrict__ We1, const float* __restrict__ Wn1,
                            const float* __restrict__ Wn2, const float* __restrict__ We2,
                            __bf16* __restrict__ WE1F, __bf16* __restrict__ WN1F,
                            __bf16* __restrict__ WN2F, __bf16* __restrict__ WE2F) {
    int idx = blockIdx.x * 256 + threadIdx.x;
    const int T1 = NLAYER * WE1F_L;
    if (idx < T1) {
        int l  = idx / WE1F_L;
        int r  = idx % WE1F_L;
        int ct = r / 1024;
        int r2 = r % 1024;
        int kh = r2 / 512;
        int r3 = r2 % 512;
        int lane = r3 >> 3, jj = r3 & 7;
        int half = ct / 17, ctl = ct % 17;
        int col = ctl * 16 + (lane & 15);
        int k = kh * 32 + (lane >> 4) * 8 + jj;
        float v = 0.f;
        if (col < EHD) v = We1[((size_t)l * EIN + (half ? 64 + k : k)) * EHD + col];
        WE1F[idx] = (__bf16)v;
        return;
    }
    idx -= T1;
    const int T2 = NLAYER * WN1F_L;
    if (idx < T2) {
        int l  = idx / WN1F_L;
        int r  = idx % WN1F_L;
        int ct = r / 1536;
        int r2 = r % 1536;
        int kt = r2 / 512;
        int r3 = r2 % 512;
        int lane = r3 >> 3, jj = r3 & 7;
        int col = ct * 16 + (lane & 15);
        int k = kt * 32 + (lane >> 4) * 8 + jj;
        float v = (k < NIN) ? Wn1[((size_t)l * NIN + k) * NHD + col] : 0.f;
        WN1F[idx] = (__bf16)v;
        return;
    }
    idx -= T2;
    const int T3 = NLAYER * WN2F_L;
    if (idx < T3) {
        int l  = idx / WN2F_L;
        int r  = idx % WN2F_L;
        int ct = r / 2048;
        int r2 = r % 2048;
        int kt = r2 / 512;
        int r3 = r2 % 512;
        int lane = r3 >> 3, jj = r3 & 7;
        int col = ct * 16 + (lane & 15);
        int k = kt * 32 + (lane >> 4) * 8 + jj;
        WN2F[idx] = (__bf16)Wn2[((size_t)l * NHD + k) * NDIM + col];
        return;
    }
    idx -= T3;
    const int T4 = NLAYER * WE2F_L;
    if (idx < T4) {
        int l  = idx / WE2F_L;
        int r  = idx % WE2F_L;
        int kt = r / 512;
        int r3 = r % 512;
        int lane = r3 >> 3, jj = r3 & 7;
        int m = lane & 15;
        int k = kt * 32 + (lane >> 4) * 8 + jj;
        float v = (k < EHD) ? We2[((size_t)l * EHD + k) * MDIM + m] * (1.0f / FP8_SCALE) : 0.f;
        WE2F[idx] = (__bf16)v;
    }
}

// ---------------- init: embedding lookup + pos copy ----------------
__global__ void init_kernel(const int* __restrict__ feats, const float* __restrict__ coors,
                            const float* __restrict__ emb,
                            float* __restrict__ x, float* __restrict__ pos, int N) {
    int idx = blockIdx.x * 256 + threadIdx.x;
    int nx = N * NDIM;
    if (idx < nx) {
        int n = idx >> 6, c = idx & 63;
        x[idx] = emb[feats[n] * NDIM + c];
    } else {
        int j = idx - nx;
        if (j < N * 3) pos[j] = coors[j];
    }
}

// ---------------- counting sort by target ----------------
__global__ void hist_kernel(const int* __restrict__ ei, int* __restrict__ cnt, int E) {
    int e = blockIdx.x * 256 + threadIdx.x;
    if (e < E) atomicAdd(&cnt[ei[E + e]], 1);
}

// multi-block exclusive scan: sum -> top-scan -> finalize
__global__ void scan_sum_kernel(const int* __restrict__ cnt, int* __restrict__ bsum, int N) {
    __shared__ int ws[4];
    int i = blockIdx.x * 256 + threadIdx.x;
    int v = (i < N) ? cnt[i] : 0;
    #pragma unroll
    for (int off = 32; off; off >>= 1) v += __shfl_down(v, off);
    int lane = threadIdx.x & 63, w = threadIdx.x >> 6;
    if (lane == 0) ws[w] = v;
    __syncthreads();
    if (threadIdx.x == 0) bsum[blockIdx.x] = ws[0] + ws[1] + ws[2] + ws[3];
}
__global__ void __launch_bounds__(1024) scan_top_kernel(int* __restrict__ bsum, int nb) {
    __shared__ int ws[16];
    int tid = threadIdx.x, lane = tid & 63, w = tid >> 6;
    int v = (tid < nb) ? bsum[tid] : 0;
    int sc = v;
    #pragma unroll
    for (int off = 1; off < 64; off <<= 1) {
        int u = __shfl_up(sc, off);
        if (lane >= off) sc += u;
    }
    if (lane == 63) ws[w] = sc;
    __syncthreads();
    int woff = 0;
    #pragma unroll
    for (int k = 0; k < 16; ++k) woff += (k < w) ? ws[k] : 0;
    if (tid < nb) bsum[tid] = woff + sc - v;   // exclusive
}
__global__ void scan_fin_kernel(const int* __restrict__ cnt, const int* __restrict__ bsum,
                                int* __restrict__ cursor, int N) {
    __shared__ int ws[4];
    int i = blockIdx.x * 256 + threadIdx.x;
    int tid = threadIdx.x, lane = tid & 63, w = tid >> 6;
    int v = (i < N) ? cnt[i] : 0;
    int sc = v;
    #pragma unroll
    for (int off = 1; off < 64; off <<= 1) {
        int u = __shfl_up(sc, off);
        if (lane >= off) sc += u;
    }
    if (lane == 63) ws[w] = sc;
    __syncthreads();
    int woff = 0;
    #pragma unroll
    for (int k = 0; k < 4; ++k) woff += (k < w) ? ws[k] : 0;
    if (i < N) cursor[i] = bsum[blockIdx.x] + woff + sc - v;
}

__global__ void scatter_kernel(const int* __restrict__ ei, int* __restrict__ cursor,
                               uint2* __restrict__ sorted_st, int E) {
    int e = blockIdx.x * 256 + threadIdx.x;
    if (e >= E) return;
    int s = ei[e], t = ei[E + e];
    int p = atomicAdd(&cursor[t], 1);
    uint2 st; st.x = (uint32_t)s; st.y = (uint32_t)t;
    sorted_st[p] = st;
}

// ---------------- MFMA: AB table build. wave = (node16, half) -----------------
__global__ void __launch_bounds__(256) gemm_ab_mfma(
        const float* __restrict__ x, const float* __restrict__ pos,
        const bf16x8* __restrict__ WE1Fl, const float* __restrict__ be1l,
        uint8_t* __restrict__ A8, uint8_t* __restrict__ pkt, int N) {
    __shared__ __align__(16) __bf16 stg[4][16][280];
    int wave = threadIdx.x >> 6, lane = threadIdx.x & 63;
    int half = wave & 1;
    int nb = blockIdx.x * 32 + (wave >> 1) * 16;
    int lrow = lane & 15, lkg = lane >> 4;
    int row = nb + lrow; if (row >= N) row = N - 1;

    const float* xr = x + (size_t)row * NDIM + lkg * 8;
    bf16x8 a0, a1;
    #pragma unroll
    for (int j = 0; j < 8; ++j) { a0[j] = (__bf16)xr[j]; a1[j] = (__bf16)xr[32 + j]; }

    f32x4 acc[17];
    #pragma unroll
    for (int t = 0; t < 17; ++t) acc[t] = (f32x4){0.f, 0.f, 0.f, 0.f};
    const bf16x8* bf = WE1Fl + (size_t)(half * 17) * 2 * 64 + lane;
    #pragma unroll
    for (int t = 0; t < 17; ++t) {
        bf16x8 b0 = bf[(t * 2 + 0) * 64];
        bf16x8 b1 = bf[(t * 2 + 1) * 64];
        acc[t] = MFMA16(a0, b0, acc[t]);
        acc[t] = MFMA16(a1, b1, acc[t]);
    }
    #pragma unroll
    for (int t = 0; t < 17; ++t) {
        int col = t * 16 + lrow;
        float bias = (half == 0 && col < EHD) ? be1l[col] : 0.f;
        #pragma unroll
        for (int r = 0; r < 4; ++r)
            stg[wave][lkg * 4 + r][col] = (__bf16)(acc[t][r] + bias);
    }
    __syncthreads();

    int node = lane >> 2;
    int gnode = nb + node;
    const __bf16* hrow = &stg[wave][node][(lane & 3) * 64];
    if (gnode < N) {
        uint8_t* dst = A8 + (size_t)gnode * AB_STRIDE + half * 256 + (lane & 3) * 64;
        #pragma unroll
        for (int g = 0; g < 8; ++g) {
            bf16x8 hv = *(const bf16x8*)(hrow + g * 8);
            uint2 pk;
            pk.x = pk_fp8_4(clamp8((float)hv[0]), clamp8((float)hv[1]),
                            clamp8((float)hv[2]), clamp8((float)hv[3]));
            pk.y = pk_fp8_4(clamp8((float)hv[4]), clamp8((float)hv[5]),
                            clamp8((float)hv[6]), clamp8((float)hv[7]));
            *(uint2*)(dst + g * 8) = pk;
        }
    }
    if (lane < 16 && nb + lane < N) {
        int gn = nb + lane;
        const uint16_t* hr = (const uint16_t*)&stg[wave][lane][256];
        uint32_t ex = (uint32_t)hr[0] | ((uint32_t)hr[1] << 16);
        uint32_t* pk = (uint32_t*)(pkt + (size_t)gn * PKT_STRIDE);
        if (half == 0) {
            uint4 w0;
            w0.x = __float_as_uint(pos[3 * gn]);
            w0.y = __float_as_uint(pos[3 * gn + 1]);
            w0.z = __float_as_uint(pos[3 * gn + 2]);
            w0.w = ex;
            *(uint4*)pk = w0;
        } else {
            pk[4] = ex;
        }
    }
}

// ---------------- per-edge: MFMA msg GEMM + coord + segmented scatter ----------------
__global__ void __launch_bounds__(256) edge_kernel(
        const uint2* __restrict__ sorted_st,
        const uint8_t* __restrict__ A8, const uint8_t* __restrict__ pkt,
        const bf16x8* __restrict__ WE2Fl, const float* __restrict__ be2l,
        const float* __restrict__ Wc1, const float* __restrict__ bc1,
        const float* __restrict__ Wc2, const float* __restrict__ bc2,
        const float* __restrict__ w128,
        float* __restrict__ agg_msg, float* __restrict__ agg_pos, int E) {

    __shared__ __align__(16) vf2   w128p[132];          // w128 * 1024, paired
    __shared__ __align__(16) float Wc1s[MDIM * CHD];
    __shared__ __align__(16) float bc1s[CHD];
    __shared__ __align__(16) float Wc2s[CHD];
    __shared__ float msg_lds[4][64][17];                // [wave][edge][m], stride 17

    int tid  = threadIdx.x;
    int wave = tid >> 6, lane = tid & 63;
    int kg   = lane >> 4, lrow = lane & 15;

    int base = blockIdx.x * 256 + wave * 64;
    int eo = base + lane;
    bool active = (eo < E);
    int eoc = active ? eo : (E - 1);
    uint2 st = sorted_st[eoc];
    int s_own = (int)st.x;
    int t_ld  = (int)st.y;
    int t_scan = active ? t_ld : -1;

    const uint32_t* ppt = (const uint32_t*)(pkt + (size_t)t_ld  * PKT_STRIDE);
    const uint32_t* pps = (const uint32_t*)(pkt + (size_t)s_own * PKT_STRIDE);
    uint4 pt0 = *(const uint4*)ppt;
    uint4 ps0 = *(const uint4*)pps;
    uint32_t b2o = pps[4];
    uint32_t a2o = pt0.w;
    float rx = __uint_as_float(pt0.x) - __uint_as_float(ps0.x);
    float ry = __uint_as_float(pt0.y) - __uint_as_float(ps0.y);
    float rz = __uint_as_float(pt0.z) - __uint_as_float(ps0.z);
    float d2o = rx*rx + ry*ry + rz*rz;

    // B fragments for We2 (scaled 1/1024), K-tiles 0..8
    bf16x8 bw[9];
    #pragma unroll
    for (int kt = 0; kt < 9; ++kt) bw[kt] = WE2Fl[kt * 64 + lane];
    float be2m = be2l[lrow];
    float cb2  = bc2[0];

    // stage LDS
    for (int i = tid; i < 132; i += 256) {
        int k0 = i * 2;
        float lo = (k0     < EHD) ? w128[k0]     * FP8_SCALE : 0.f;
        float hi = (k0 + 1 < EHD) ? w128[k0 + 1] * FP8_SCALE : 0.f;
        w128p[i] = (vf2){lo, hi};
    }
    for (int i = tid; i < MDIM * CHD; i += 256) Wc1s[i] = Wc1[i];
    if (tid < CHD) { bc1s[tid] = bc1[tid]; Wc2s[tid] = Wc2[tid]; }
    __syncthreads();

    // ---- 4 MFMA tiles of 16 edges ----
    #pragma unroll
    for (int tt = 0; tt < 4; ++tt) {
        int srcl = tt * 16 + lrow;
        int t_r = __shfl(t_ld, srcl);
        int s_r = __shfl(s_own, srcl);
        float d2r = __shfl(d2o, srcl);
        uint32_t a2r = (uint32_t)__shfl((int)a2o, srcl);
        uint32_t b2r = (uint32_t)__shfl((int)b2o, srcl);
        vf2 d2v = (vf2){d2r, d2r};

        const uint8_t* Ar = A8 + (size_t)t_r * AB_STRIDE + kg * 8;
        const uint8_t* Br = A8 + (size_t)s_r * AB_STRIDE + 256 + kg * 8;

        f32x4 acc = (f32x4){0.f, 0.f, 0.f, 0.f};
        #pragma unroll
        for (int kt = 0; kt < 8; ++kt) {
            uint2 ad = *(const uint2*)(Ar + kt * 32);
            uint2 bd = *(const uint2*)(Br + kt * 32);
            const vf2* wp = &w128p[kt * 16 + kg * 4];
            vf2 u0 = __builtin_amdgcn_cvt_pk_f32_fp8(ad.x, false)
                   + __builtin_amdgcn_cvt_pk_f32_fp8(bd.x, false) + d2v * wp[0];
            vf2 u1 = __builtin_amdgcn_cvt_pk_f32_fp8(ad.x, true)
                   + __builtin_amdgcn_cvt_pk_f32_fp8(bd.x, true)  + d2v * wp[1];
            vf2 u2 = __builtin_amdgcn_cvt_pk_f32_fp8(ad.y, false)
                   + __builtin_amdgcn_cvt_pk_f32_fp8(bd.y, false) + d2v * wp[2];
            vf2 u3 = __builtin_amdgcn_cvt_pk_f32_fp8(ad.y, true)
                   + __builtin_amdgcn_cvt_pk_f32_fp8(bd.y, true)  + d2v * wp[3];
            bf16x8 af;
            af[0] = (__bf16)hprime_f(u0.x); af[1] = (__bf16)hprime_f(u0.y);
            af[2] = (__bf16)hprime_f(u1.x); af[3] = (__bf16)hprime_f(u1.y);
            af[4] = (__bf16)hprime_f(u2.x); af[5] = (__bf16)hprime_f(u2.y);
            af[6] = (__bf16)hprime_f(u3.x); af[7] = (__bf16)hprime_f(u3.y);
            acc = MFMA16(af, bw[kt], acc);
        }
        // extras K-tile (k=256,257 nonzero only, kg==0 jj 0,1)
        {
            float h0 = 0.f, h1 = 0.f;
            if (kg == 0) {
                vf2 wx = w128p[128];
                float u0 = (bflo(a2r) + bflo(b2r)) * FP8_SCALE + d2r * wx.x;
                float u1 = (bfhi(a2r) + bfhi(b2r)) * FP8_SCALE + d2r * wx.y;
                h0 = hprime_f(u0);
                h1 = hprime_f(u1);
            }
            bf16x8 af;
            af[0] = (__bf16)h0; af[1] = (__bf16)h1;
            #pragma unroll
            for (int j = 2; j < 8; ++j) af[j] = (__bf16)0.f;
            acc = MFMA16(af, bw[8], acc);
        }
        // epilogue: bias + silu, write to LDS transpose buffer
        #pragma unroll
        for (int r = 0; r < 4; ++r) {
            float mval = silu_f(acc[r] + be2m);
            msg_lds[wave][tt * 16 + kg * 4 + r][lrow] = mval;
        }
    }
    __syncthreads();

    // ---- per-lane (edge = eo): coord MLP + segmented scan + atomics ----
    float vals[19];
    vf2 msp[MDIM];
    #pragma unroll
    for (int m = 0; m < MDIM; ++m) {
        float v = msg_lds[wave][lane][m];
        vals[m] = v;
        msp[m] = (vf2){v, v};
    }

    const vf2* bc1v = (const vf2*)bc1s;
    const vf2* wc2v = (const vf2*)Wc2s;
    vf2 cwacc = (vf2){0.f, 0.f};
    #pragma unroll 4
    for (int cp = 0; cp < CHD / 2; ++cp) {
        vf2 tacc = bc1v[cp];
        #pragma unroll
        for (int m = 0; m < MDIM; ++m) {
            vf2 w = *(const vf2*)&Wc1s[m * CHD + 2 * cp];
            tacc += msp[m] * w;
        }
        vf2 hs;
        hs.x = silu_f(tacc.x);
        hs.y = silu_f(tacc.y);
        cwacc += hs * wc2v[cp];
    }
    float cw = cb2 + cwacc.x + cwacc.y;
    vals[16] = rx * cw;
    vals[17] = ry * cw;
    vals[18] = rz * cw;

    #pragma unroll
    for (int off = 1; off < 64; off <<= 1) {
        int tu = __shfl_up(t_scan, off);
        bool same = (lane >= off) && (tu == t_scan);
        #pragma unroll
        for (int v = 0; v < 19; ++v) {
            float vu = __shfl_up(vals[v], off);
            vals[v] += same ? vu : 0.f;
        }
    }
    int tn = __shfl_down(t_scan, 1);
    bool last = (lane == 63) || (tn != t_scan);
    if (active && last) {
        float* am = agg_msg + (size_t)t_scan * MDIM;
        #pragma unroll
        for (int m = 0; m < MDIM; ++m) atomicAdd(&am[m], vals[m]);
        atomicAdd(&agg_pos[3*t_scan],   vals[16]);
        atomicAdd(&agg_pos[3*t_scan+1], vals[17]);
        atomicAdd(&agg_pos[3*t_scan+2], vals[18]);
    }
}

// ---------------- MFMA node MLP + residual + pos update ----------------
__global__ void __launch_bounds__(256) node_mfma(
        float* __restrict__ x, float* __restrict__ pos,
        const float* __restrict__ agg_msg, const float* __restrict__ agg_pos,
        const bf16x8* __restrict__ WN1Fl, const bf16x8* __restrict__ WN2Fl,
        const float* __restrict__ bn1l, const float* __restrict__ bn2l, int N) {
    __shared__ __align__(16) __bf16 stg[4][16][136];
    int wave = threadIdx.x >> 6, lane = threadIdx.x & 63;
    int nb = blockIdx.x * 64 + wave * 16;
    int lrow = lane & 15, lkg = lane >> 4;
    int row = nb + lrow;
    int rc = (row < N) ? row : (N - 1);

    const float* xr = x + (size_t)rc * NDIM + lkg * 8;
    bf16x8 a0, a1, a2;
    #pragma unroll
    for (int j = 0; j < 8; ++j) { a0[j] = (__bf16)xr[j]; a1[j] = (__bf16)xr[32 + j]; }
    if (lkg < 2) {
        const float* mr = agg_msg + (size_t)rc * MDIM + lkg * 8;
        #pragma unroll
        for (int j = 0; j < 8; ++j) a2[j] = (__bf16)mr[j];
    } else {
        #pragma unroll
        for (int j = 0; j < 8; ++j) a2[j] = (__bf16)0.f;
    }

    f32x4 h[8];
    #pragma unroll
    for (int t = 0; t < 8; ++t) h[t] = (f32x4){0.f, 0.f, 0.f, 0.f};
    const bf16x8* b1 = WN1Fl + lane;
    #pragma unroll
    for (int t = 0; t < 8; ++t) {
        h[t] = MFMA16(a0, b1[(t * 3 + 0) * 64], h[t]);
        h[t] = MFMA16(a1, b1[(t * 3 + 1) * 64], h[t]);
        h[t] = MFMA16(a2, b1[(t * 3 + 2) * 64], h[t]);
    }
    #pragma unroll
    for (int t = 0; t < 8; ++t) {
        int col = t * 16 + lrow;
        float bias = bn1l[col];
        #pragma unroll
        for (int r = 0; r < 4; ++r)
            stg[wave][lkg * 4 + r][col] = (__bf16)silu_f(h[t][r] + bias);
    }
    __syncthreads();

    bf16x8 af[4];
    #pragma unroll
    for (int kt = 0; kt < 4; ++kt)
        af[kt] = *(const bf16x8*)&stg[wave][lrow][kt * 32 + lkg * 8];

    f32x4 o[4];
    #pragma unroll
    for (int t = 0; t < 4; ++t) o[t] = (f32x4){0.f, 0.f, 0.f, 0.f};
    const bf16x8* b2 = WN2Fl + lane;
    #pragma unroll
    for (int t = 0; t < 4; ++t) {
        #pragma unroll
        for (int kt = 0; kt < 4; ++kt)
            o[t] = MFMA16(af[kt], b2[(t * 4 + kt) * 64], o[t]);
    }

    int orow = nb + lkg * 4;
    #pragma unroll
    for (int t = 0; t < 4; ++t) {
        int col = t * 16 + lrow;
        float bias = bn2l[col];
        #pragma unroll
        for (int r = 0; r < 4; ++r) {
            int rr = orow + r;
            if (rr < N) x[(size_t)rr * NDIM + col] += o[t][r] + bias;
        }
    }
    if (threadIdx.x < 192) {
        long j = (long)blockIdx.x * 192 + threadIdx.x;
        if (j < (long)N * 3) pos[j] += agg_pos[j];
    }
}

// ---------------- host launch ----------------
extern "C" void kernel_launch(void* const* d_in, const int* in_sizes, int n_in,
                              void* d_out, int out_size, void* d_ws, size_t ws_size,
                              hipStream_t stream) {
    const int*   feats = (const int*)  d_in[0];
    const float* coors = (const float*)d_in[1];
    const int*   ei    = (const int*)  d_in[2];
    const float* emb   = (const float*)d_in[3];
    const float* We1   = (const float*)d_in[4];
    const float* be1   = (const float*)d_in[5];
    const float* We2   = (const float*)d_in[6];
    const float* be2   = (const float*)d_in[7];
    const float* Wc1   = (const float*)d_in[8];
    const float* bc1   = (const float*)d_in[9];
    const float* Wc2   = (const float*)d_in[10];
    const float* bc2   = (const float*)d_in[11];
    const float* Wn1   = (const float*)d_in[12];
    const float* bn1   = (const float*)d_in[13];
    const float* Wn2   = (const float*)d_in[14];
    const float* bn2   = (const float*)d_in[15];

    const int N = in_sizes[0];
    const int E = in_sizes[2] / 2;

    float* x   = (float*)d_out;                     // [N,64]
    float* pos = (float*)d_out + (size_t)N * NDIM;  // [N,3]

    // workspace layout
    char* w = (char*)d_ws;
    uint8_t* A8 = (uint8_t*)w;                                  // N*512
    size_t off = ((size_t)N * AB_STRIDE + 255) & ~(size_t)255;
    uint8_t* pkt = (uint8_t*)(w + off);                         // N*32
    off += ((size_t)N * PKT_STRIDE + 255) & ~(size_t)255;
    float* agg_msg = (float*)(w + off);                         // N*16
    off += ((size_t)N * MDIM * 4 + 255) & ~(size_t)255;
    float* agg_pos = (float*)(w + off);                         // N*3
    off += ((size_t)N * 3 * 4 + 255) & ~(size_t)255;
    uint2* sorted_st = (uint2*)(w + off);                       // E*8
    off += ((size_t)E * 8 + 255) & ~(size_t)255;
    int* cnt = (int*)(w + off);                                 // N
    off += ((size_t)N * 4 + 255) & ~(size_t)255;
    int* cursor = (int*)(w + off);                              // N
    off += ((size_t)N * 4 + 255) & ~(size_t)255;
    int* bsum = (int*)(w + off);                                // ceil(N/256)
    off += (((size_t)N / 256 + 2) * 4 + 255) & ~(size_t)255;
    __bf16* WE1F = (__bf16*)(w + off);
    off += ((size_t)NLAYER * WE1F_L * 2 + 255) & ~(size_t)255;
    __bf16* WN1F = (__bf16*)(w + off);
    off += ((size_t)NLAYER * WN1F_L * 2 + 255) & ~(size_t)255;
    __bf16* WN2F = (__bf16*)(w + off);
    off += ((size_t)NLAYER * WN2F_L * 2 + 255) & ~(size_t)255;
    __bf16* WE2F = (__bf16*)(w + off);
    (void)ws_size; (void)n_in; (void)out_size;

    {
        int total = NLAYER * (WE1F_L + WN1F_L + WN2F_L + WE2F_L);
        prep_kernel<<<(total + 255) / 256, 256, 0, stream>>>(We1, Wn1, Wn2, We2,
                                                             WE1F, WN1F, WN2F, WE2F);
    }
    {
        int total = N * (NDIM + 3);
        init_kernel<<<(total + 255) / 256, 256, 0, stream>>>(feats, coors, emb, x, pos, N);
    }
    // counting sort by target (once; edge_index constant across layers)
    hipMemsetAsync(cnt, 0, (size_t)N * 4, stream);
    hist_kernel<<<(E + 255) / 256, 256, 0, stream>>>(ei, cnt, E);
    {
        int nb = (N + 255) / 256;
        scan_sum_kernel<<<nb, 256, 0, stream>>>(cnt, bsum, N);
        scan_top_kernel<<<1, 1024, 0, stream>>>(bsum, nb);
        scan_fin_kernel<<<nb, 256, 0, stream>>>(cnt, bsum, cursor, N);
    }
    scatter_kernel<<<(E + 255) / 256, 256, 0, stream>>>(ei, cursor, sorted_st, E);

    for (int l = 0; l < NLAYER; ++l) {
        const float* We1_l  = We1 + (size_t)l * EIN * EHD;
        const float* w128_l = We1_l + (size_t)128 * EHD;

        gemm_ab_mfma<<<(N + 31) / 32, 256, 0, stream>>>(
            x, pos, (const bf16x8*)(WE1F + (size_t)l * WE1F_L),
            be1 + (size_t)l * EHD, A8, pkt, N);

        hipMemsetAsync(agg_msg, 0, (size_t)N * MDIM * 4, stream);
        hipMemsetAsync(agg_pos, 0, (size_t)N * 3 * 4, stream);

        edge_kernel<<<(E + 255) / 256, 256, 0, stream>>>(
            sorted_st, A8, pkt,
            (const bf16x8*)(WE2F + (size_t)l * WE2F_L), be2 + (size_t)l * MDIM,
            Wc1 + (size_t)l * MDIM * CHD, bc1 + (size_t)l * CHD,
            Wc2 + (size_t)l * CHD, bc2 + l, w128_l,
            agg_msg, agg_pos, E);

        node_mfma<<<(N + 63) / 64, 256, 0, stream>>>(
            x, pos, agg_msg, agg_pos,
            (const bf16x8*)(WN1F + (size_t)l * WN1F_L),
            (const bf16x8*)(WN2F + (size_t)l * WN2F_L),
            bn1 + (size_t)l * NHD, bn2 + (size_t)l * NDIM, N);
    }
}

// Round 6
// 1047.214 us; speedup vs baseline: 7.0901x; 1.1874x over previous
//
#include <hip/hip_runtime.h>
#include <hip/hip_bf16.h>
#include <stdint.h>

#define NDIM   64     // node channels D
#define MDIM   16     // msg channels
#define NLAYER 3
#define EIN    129    // 2D+1
#define EHD    258    // edge hidden
#define CHD    64     // coord hidden
#define NHD    128    // node hidden
#define NIN    80     // D + M
#define AB_STRIDE 512 // bytes per node in fp8 AB table (A 256B | B 256B)
#define PKT_STRIDE 32 // bytes per node packet: pos xyz f32, a2 bf16x2, b2 bf16x2
#define FP8_SCALE 1024.0f
#define NVALS  19     // 16 msg + 3 pos channels aggregated per edge

// fragment-table element counts (per layer, in bf16 elems)
#define WE1F_L (34*2*512)   // 34816
#define WN1F_L (8*3*512)    // 12288
#define WN2F_L (4*4*512)    // 8192
#define WE2F_L (9*512)      // 4608: [kt(9)][lane(64)][jj(8)] = We2[k][m]/1024
#define WC1F_L (4*512)      // 2048: [ct(4)][lane(64)][jj(8)] = Wc1[k<16][ct*16+col]

typedef float vf2 __attribute__((ext_vector_type(2)));
typedef __bf16 bf16x8 __attribute__((ext_vector_type(8)));
typedef float  f32x4  __attribute__((ext_vector_type(4)));

#define MFMA16(a, b, c) __builtin_amdgcn_mfma_f32_16x16x32_bf16((a), (b), (c), 0, 0, 0)

__device__ __forceinline__ float rcp_f(float x) { return __builtin_amdgcn_rcpf(x); }
#if __has_builtin(__builtin_amdgcn_exp2f)
__device__ __forceinline__ float exp2_f(float x) { return __builtin_amdgcn_exp2f(x); }
#else
__device__ __forceinline__ float exp2_f(float x) { return __expf(x * 0.6931471805599453f); }
#endif
__device__ __forceinline__ float silu_f(float v) {
    return v * rcp_f(1.0f + __expf(-v));
}
// h' = u * sigmoid(u/1024)  (u = 1024*pre_h); CC = -log2(e)/1024
#define CC_EXP (-1.4426950408889634f / 1024.0f)
__device__ __forceinline__ float hprime_f(float u) {
    return u * rcp_f(1.0f + exp2_f(CC_EXP * u));
}
__device__ __forceinline__ float bflo(uint32_t u) {
    union { uint32_t u; float f; } c; c.u = u << 16; return c.f;
}
__device__ __forceinline__ float bfhi(uint32_t u) {
    union { uint32_t u; float f; } c; c.u = u & 0xffff0000u; return c.f;
}
__device__ __forceinline__ uint32_t pk_fp8_4(float f0, float f1, float f2, float f3) {
    uint32_t r = (uint32_t)__builtin_amdgcn_cvt_pk_fp8_f32(f0, f1, 0, false);
    r = (uint32_t)__builtin_amdgcn_cvt_pk_fp8_f32(f2, f3, (int)r, true);
    return r;
}
__device__ __forceinline__ float clamp8(float v) {
    return fminf(448.0f, fmaxf(-448.0f, v * FP8_SCALE));
}

// ---------------- prep: weights -> MFMA fragment order (bf16) ----------------
__global__ void prep_kernel(const float* __restrict__ We1, const float* __restrict__ Wn1,
                            const float* __restrict__ Wn2, const float* __restrict__ We2,
                            const float* __restrict__ Wc1,
                            __bf16* __restrict__ WE1F, __bf16* __restrict__ WN1F,
                            __bf16* __restrict__ WN2F, __bf16* __restrict__ WE2F,
                            __bf16* __restrict__ WC1F) {
    int idx = blockIdx.x * 256 + threadIdx.x;
    const int T1 = NLAYER * WE1F_L;
    if (idx < T1) {
        int l  = idx / WE1F_L;
        int r  = idx % WE1F_L;
        int ct = r / 1024;
        int r2 = r % 1024;
        int kh = r2 / 512;
        int r3 = r2 % 512;
        int lane = r3 >> 3, jj = r3 & 7;
        int half = ct / 17, ctl = ct % 17;
        int col = ctl * 16 + (lane & 15);
        int k = kh * 32 + (lane >> 4) * 8 + jj;
        float v = 0.f;
        if (col < EHD) v = We1[((size_t)l * EIN + (half ? 64 + k : k)) * EHD + col];
        WE1F[idx] = (__bf16)v;
        return;
    }
    idx -= T1;
    const int T2 = NLAYER * WN1F_L;
    if (idx < T2) {
        int l  = idx / WN1F_L;
        int r  = idx % WN1F_L;
        int ct = r / 1536;
        int r2 = r % 1536;
        int kt = r2 / 512;
        int r3 = r2 % 512;
        int lane = r3 >> 3, jj = r3 & 7;
        int col = ct * 16 + (lane & 15);
        int k = kt * 32 + (lane >> 4) * 8 + jj;
        float v = (k < NIN) ? Wn1[((size_t)l * NIN + k) * NHD + col] : 0.f;
        WN1F[idx] = (__bf16)v;
        return;
    }
    idx -= T2;
    const int T3 = NLAYER * WN2F_L;
    if (idx < T3) {
        int l  = idx / WN2F_L;
        int r  = idx % WN2F_L;
        int ct = r / 2048;
        int r2 = r % 2048;
        int kt = r2 / 512;
        int r3 = r2 % 512;
        int lane = r3 >> 3, jj = r3 & 7;
        int col = ct * 16 + (lane & 15);
        int k = kt * 32 + (lane >> 4) * 8 + jj;
        WN2F[idx] = (__bf16)Wn2[((size_t)l * NHD + k) * NDIM + col];
        return;
    }
    idx -= T3;
    const int T4 = NLAYER * WE2F_L;
    if (idx < T4) {
        int l  = idx / WE2F_L;
        int r  = idx % WE2F_L;
        int kt = r / 512;
        int r3 = r % 512;
        int lane = r3 >> 3, jj = r3 & 7;
        int m = lane & 15;
        int k = kt * 32 + (lane >> 4) * 8 + jj;
        float v = (k < EHD) ? We2[((size_t)l * EHD + k) * MDIM + m] * (1.0f / FP8_SCALE) : 0.f;
        WE2F[idx] = (__bf16)v;
        return;
    }
    idx -= T4;
    const int T5 = NLAYER * WC1F_L;
    if (idx < T5) {
        int l  = idx / WC1F_L;
        int r  = idx % WC1F_L;
        int ct = r / 512;
        int r3 = r % 512;
        int lane = r3 >> 3, jj = r3 & 7;
        int c = ct * 16 + (lane & 15);
        int k = (lane >> 4) * 8 + jj;        // K=32 tile, only k<16 valid
        float v = (k < MDIM) ? Wc1[((size_t)l * MDIM + k) * CHD + c] : 0.f;
        WC1F[idx] = (__bf16)v;
    }
}

// ---------------- init: embedding lookup + pos copy ----------------
__global__ void init_kernel(const int* __restrict__ feats, const float* __restrict__ coors,
                            const float* __restrict__ emb,
                            float* __restrict__ x, float* __restrict__ pos, int N) {
    int idx = blockIdx.x * 256 + threadIdx.x;
    int nx = N * NDIM;
    if (idx < nx) {
        int n = idx >> 6, c = idx & 63;
        x[idx] = emb[feats[n] * NDIM + c];
    } else {
        int j = idx - nx;
        if (j < N * 3) pos[j] = coors[j];
    }
}

// ---------------- counting sort by target ----------------
__global__ void hist_kernel(const int* __restrict__ ei, int* __restrict__ cnt, int E) {
    int e = blockIdx.x * 256 + threadIdx.x;
    if (e < E) atomicAdd(&cnt[ei[E + e]], 1);
}

__global__ void scan_sum_kernel(const int* __restrict__ cnt, int* __restrict__ bsum, int N) {
    __shared__ int ws[4];
    int i = blockIdx.x * 256 + threadIdx.x;
    int v = (i < N) ? cnt[i] : 0;
    #pragma unroll
    for (int off = 32; off; off >>= 1) v += __shfl_down(v, off);
    int lane = threadIdx.x & 63, w = threadIdx.x >> 6;
    if (lane == 0) ws[w] = v;
    __syncthreads();
    if (threadIdx.x == 0) bsum[blockIdx.x] = ws[0] + ws[1] + ws[2] + ws[3];
}
__global__ void __launch_bounds__(1024) scan_top_kernel(int* __restrict__ bsum, int nb) {
    __shared__ int ws[16];
    int tid = threadIdx.x, lane = tid & 63, w = tid >> 6;
    int v = (tid < nb) ? bsum[tid] : 0;
    int sc = v;
    #pragma unroll
    for (int off = 1; off < 64; off <<= 1) {
        int u = __shfl_up(sc, off);
        if (lane >= off) sc += u;
    }
    if (lane == 63) ws[w] = sc;
    __syncthreads();
    int woff = 0;
    #pragma unroll
    for (int k = 0; k < 16; ++k) woff += (k < w) ? ws[k] : 0;
    if (tid < nb) bsum[tid] = woff + sc - v;   // exclusive
}
__global__ void scan_fin_kernel(const int* __restrict__ cnt, const int* __restrict__ bsum,
                                int* __restrict__ cursor, int N) {
    __shared__ int ws[4];
    int i = blockIdx.x * 256 + threadIdx.x;
    int tid = threadIdx.x, lane = tid & 63, w = tid >> 6;
    int v = (i < N) ? cnt[i] : 0;
    int sc = v;
    #pragma unroll
    for (int off = 1; off < 64; off <<= 1) {
        int u = __shfl_up(sc, off);
        if (lane >= off) sc += u;
    }
    if (lane == 63) ws[w] = sc;
    __syncthreads();
    int woff = 0;
    #pragma unroll
    for (int k = 0; k < 4; ++k) woff += (k < w) ? ws[k] : 0;
    if (i < N) cursor[i] = bsum[blockIdx.x] + woff + sc - v;
}

__global__ void scatter_kernel(const int* __restrict__ ei, int* __restrict__ cursor,
                               uint2* __restrict__ sorted_st, int E) {
    int e = blockIdx.x * 256 + threadIdx.x;
    if (e >= E) return;
    int s = ei[e], t = ei[E + e];
    int p = atomicAdd(&cursor[t], 1);
    uint2 st; st.x = (uint32_t)s; st.y = (uint32_t)t;
    sorted_st[p] = st;
}

// ---------------- MFMA: AB table build + agg zeroing. wave = (node16, half) ---
__global__ void __launch_bounds__(256) gemm_ab_mfma(
        const float* __restrict__ x, const float* __restrict__ pos,
        const bf16x8* __restrict__ WE1Fl, const float* __restrict__ be1l,
        uint8_t* __restrict__ A8, uint8_t* __restrict__ pkt,
        float* __restrict__ agg_msg, float* __restrict__ agg_pos, int N) {
    __shared__ __align__(16) __bf16 stg[4][16][280];
    int wave = threadIdx.x >> 6, lane = threadIdx.x & 63;
    int half = wave & 1;
    int nb = blockIdx.x * 32 + (wave >> 1) * 16;
    int lrow = lane & 15, lkg = lane >> 4;
    int row = nb + lrow; if (row >= N) row = N - 1;

    const float* xr = x + (size_t)row * NDIM + lkg * 8;
    bf16x8 a0, a1;
    #pragma unroll
    for (int j = 0; j < 8; ++j) { a0[j] = (__bf16)xr[j]; a1[j] = (__bf16)xr[32 + j]; }

    f32x4 acc[17];
    #pragma unroll
    for (int t = 0; t < 17; ++t) acc[t] = (f32x4){0.f, 0.f, 0.f, 0.f};
    const bf16x8* bf = WE1Fl + (size_t)(half * 17) * 2 * 64 + lane;
    #pragma unroll
    for (int t = 0; t < 17; ++t) {
        bf16x8 b0 = bf[(t * 2 + 0) * 64];
        bf16x8 b1 = bf[(t * 2 + 1) * 64];
        acc[t] = MFMA16(a0, b0, acc[t]);
        acc[t] = MFMA16(a1, b1, acc[t]);
    }
    #pragma unroll
    for (int t = 0; t < 17; ++t) {
        int col = t * 16 + lrow;
        float bias = (half == 0 && col < EHD) ? be1l[col] : 0.f;
        #pragma unroll
        for (int r = 0; r < 4; ++r)
            stg[wave][lkg * 4 + r][col] = (__bf16)(acc[t][r] + bias);
    }
    __syncthreads();

    int node = lane >> 2;
    int gnode = nb + node;
    const __bf16* hrow = &stg[wave][node][(lane & 3) * 64];
    if (gnode < N) {
        uint8_t* dst = A8 + (size_t)gnode * AB_STRIDE + half * 256 + (lane & 3) * 64;
        #pragma unroll
        for (int g = 0; g < 8; ++g) {
            bf16x8 hv = *(const bf16x8*)(hrow + g * 8);
            uint2 pk;
            pk.x = pk_fp8_4(clamp8((float)hv[0]), clamp8((float)hv[1]),
                            clamp8((float)hv[2]), clamp8((float)hv[3]));
            pk.y = pk_fp8_4(clamp8((float)hv[4]), clamp8((float)hv[5]),
                            clamp8((float)hv[6]), clamp8((float)hv[7]));
            *(uint2*)(dst + g * 8) = pk;
        }
    }
    if (lane < 16 && nb + lane < N) {
        int gn = nb + lane;
        const uint16_t* hr = (const uint16_t*)&stg[wave][lane][256];
        uint32_t ex = (uint32_t)hr[0] | ((uint32_t)hr[1] << 16);
        uint32_t* pk = (uint32_t*)(pkt + (size_t)gn * PKT_STRIDE);
        if (half == 0) {
            uint4 w0;
            w0.x = __float_as_uint(pos[3 * gn]);
            w0.y = __float_as_uint(pos[3 * gn + 1]);
            w0.z = __float_as_uint(pos[3 * gn + 2]);
            w0.w = ex;
            *(uint4*)pk = w0;
        } else {
            pk[4] = ex;
        }
    }
    // zero agg buffers for this block's 32-node range (replaces hipMemsetAsync)
    {
        int i16 = blockIdx.x * 512 + (int)threadIdx.x * 2;   // 32 nodes * 16 ch
        if (i16 + 1 < N * MDIM) {
            *(vf2*)(agg_msg + i16) = (vf2){0.f, 0.f};
        } else if (i16 < N * MDIM) {
            agg_msg[i16] = 0.f;
        }
        if (threadIdx.x < 96) {
            int ip = blockIdx.x * 96 + (int)threadIdx.x;     // 32 nodes * 3
            if (ip < N * 3) agg_pos[ip] = 0.f;
        }
    }
}

// ---------------- per-edge: MFMA msg GEMM + MFMA coord + run-reduce scatter ----------------
__global__ void __launch_bounds__(256) edge_kernel(
        const uint2* __restrict__ sorted_st,
        const uint8_t* __restrict__ A8, const uint8_t* __restrict__ pkt,
        const bf16x8* __restrict__ WE2Fl, const bf16x8* __restrict__ WC1Fl,
        const float* __restrict__ be2l,
        const float* __restrict__ bc1, const float* __restrict__ Wc2,
        const float* __restrict__ bc2, const float* __restrict__ w128,
        float* __restrict__ agg_msg, float* __restrict__ agg_pos, int E) {

    __shared__ __align__(16) vf2    w128p[132];        // w128 * 1024, paired
    __shared__ __align__(16) __bf16 msg_lds[4][64][24];// [wave][edge][ch] 0-15 msg,16-18 r*cw
    __shared__ int  run_t[4][64];
    __shared__ uint run_se[4][64];

    int tid  = threadIdx.x;
    int wave = tid >> 6, lane = tid & 63;
    int kg   = lane >> 4, lrow = lane & 15;

    int base = blockIdx.x * 256 + wave * 64;
    int eo = base + lane;
    bool active = (eo < E);
    int eoc = active ? eo : (E - 1);
    uint2 st = sorted_st[eoc];
    int s_own = (int)st.x;
    int t_ld  = (int)st.y;
    int t_scan = active ? t_ld : -1;

    const uint32_t* ppt = (const uint32_t*)(pkt + (size_t)t_ld  * PKT_STRIDE);
    const uint32_t* pps = (const uint32_t*)(pkt + (size_t)s_own * PKT_STRIDE);
    uint4 pt0 = *(const uint4*)ppt;
    uint4 ps0 = *(const uint4*)pps;
    uint32_t b2o = pps[4];
    uint32_t a2o = pt0.w;
    float rx = __uint_as_float(pt0.x) - __uint_as_float(ps0.x);
    float ry = __uint_as_float(pt0.y) - __uint_as_float(ps0.y);
    float rz = __uint_as_float(pt0.z) - __uint_as_float(ps0.z);
    float d2o = rx*rx + ry*ry + rz*rz;

    // hoisted fragments / scalars (hot L1 lines)
    bf16x8 bw[9];
    #pragma unroll
    for (int kt = 0; kt < 9; ++kt) bw[kt] = WE2Fl[kt * 64 + lane];
    bf16x8 bwc[4];
    float bc1r[4], wc2r[4];
    #pragma unroll
    for (int ct = 0; ct < 4; ++ct) {
        bwc[ct]  = WC1Fl[ct * 64 + lane];
        bc1r[ct] = bc1[ct * 16 + lrow];
        wc2r[ct] = Wc2[ct * 16 + lrow];
    }
    float be2m = be2l[lrow];
    float cb2  = bc2[0];

    for (int i = tid; i < 132; i += 256) {
        int k0 = i * 2;
        float lo = (k0     < EHD) ? w128[k0]     * FP8_SCALE : 0.f;
        float hi = (k0 + 1 < EHD) ? w128[k0 + 1] * FP8_SCALE : 0.f;
        w128p[i] = (vf2){lo, hi};
    }
    __syncthreads();

    // ---- 4 MFMA tiles of 16 edges ----
    #pragma unroll
    for (int tt = 0; tt < 4; ++tt) {
        int srcl = tt * 16 + lrow;
        int t_r = __shfl(t_ld, srcl);
        int s_r = __shfl(s_own, srcl);
        float d2r = __shfl(d2o, srcl);
        uint32_t a2r = (uint32_t)__shfl((int)a2o, srcl);
        uint32_t b2r = (uint32_t)__shfl((int)b2o, srcl);
        vf2 d2v = (vf2){d2r, d2r};

        const uint8_t* Ar = A8 + (size_t)t_r * AB_STRIDE + kg * 8;
        const uint8_t* Br = A8 + (size_t)s_r * AB_STRIDE + 256 + kg * 8;

        f32x4 acc = (f32x4){0.f, 0.f, 0.f, 0.f};
        #pragma unroll
        for (int kt = 0; kt < 8; ++kt) {
            uint2 ad = *(const uint2*)(Ar + kt * 32);
            uint2 bd = *(const uint2*)(Br + kt * 32);
            const vf2* wp = &w128p[kt * 16 + kg * 4];
            vf2 u0 = __builtin_amdgcn_cvt_pk_f32_fp8(ad.x, false)
                   + __builtin_amdgcn_cvt_pk_f32_fp8(bd.x, false) + d2v * wp[0];
            vf2 u1 = __builtin_amdgcn_cvt_pk_f32_fp8(ad.x, true)
                   + __builtin_amdgcn_cvt_pk_f32_fp8(bd.x, true)  + d2v * wp[1];
            vf2 u2 = __builtin_amdgcn_cvt_pk_f32_fp8(ad.y, false)
                   + __builtin_amdgcn_cvt_pk_f32_fp8(bd.y, false) + d2v * wp[2];
            vf2 u3 = __builtin_amdgcn_cvt_pk_f32_fp8(ad.y, true)
                   + __builtin_amdgcn_cvt_pk_f32_fp8(bd.y, true)  + d2v * wp[3];
            bf16x8 af;
            af[0] = (__bf16)hprime_f(u0.x); af[1] = (__bf16)hprime_f(u0.y);
            af[2] = (__bf16)hprime_f(u1.x); af[3] = (__bf16)hprime_f(u1.y);
            af[4] = (__bf16)hprime_f(u2.x); af[5] = (__bf16)hprime_f(u2.y);
            af[6] = (__bf16)hprime_f(u3.x); af[7] = (__bf16)hprime_f(u3.y);
            acc = MFMA16(af, bw[kt], acc);
        }
        // extras K-tile (k=256,257 nonzero only, kg==0 jj 0,1)
        {
            float h0 = 0.f, h1 = 0.f;
            if (kg == 0) {
                vf2 wx = w128p[128];
                float u0 = (bflo(a2r) + bflo(b2r)) * FP8_SCALE + d2r * wx.x;
                float u1 = (bfhi(a2r) + bfhi(b2r)) * FP8_SCALE + d2r * wx.y;
                h0 = hprime_f(u0);
                h1 = hprime_f(u1);
            }
            bf16x8 af;
            af[0] = (__bf16)h0; af[1] = (__bf16)h1;
            #pragma unroll
            for (int j = 2; j < 8; ++j) af[j] = (__bf16)0.f;
            acc = MFMA16(af, bw[8], acc);
        }
        // msg = silu(acc + be2); stash bf16 to LDS (C layout: edge=kg*4+r, m=lrow)
        #pragma unroll
        for (int r = 0; r < 4; ++r) {
            float mval = silu_f(acc[r] + be2m);
            msg_lds[wave][tt * 16 + kg * 4 + r][lrow] = (__bf16)mval;
        }
        __builtin_amdgcn_wave_barrier();   // same-wave LDS producer->consumer (DS in-order)

        // ---- coord MLP via MFMA: A = msg (16e x K=32, k<16 valid) ----
        bf16x8 ac = (bf16x8){(__bf16)0.f,(__bf16)0.f,(__bf16)0.f,(__bf16)0.f,
                             (__bf16)0.f,(__bf16)0.f,(__bf16)0.f,(__bf16)0.f};
        if (kg < 2) ac = *(const bf16x8*)&msg_lds[wave][tt * 16 + lrow][kg * 8];
        f32x4 c0 = (f32x4){0.f,0.f,0.f,0.f}, c1 = c0, c2 = c0, c3 = c0;
        c0 = MFMA16(ac, bwc[0], c0);
        c1 = MFMA16(ac, bwc[1], c1);
        c2 = MFMA16(ac, bwc[2], c2);
        c3 = MFMA16(ac, bwc[3], c3);
        // silu + Wc2 dot; C layout: edge=kg*4+r, c=ct*16+lrow
        float p0 = 0.f, p1 = 0.f, p2 = 0.f, p3 = 0.f;
        p0 += silu_f(c0[0] + bc1r[0]) * wc2r[0]; p1 += silu_f(c0[1] + bc1r[0]) * wc2r[0];
        p2 += silu_f(c0[2] + bc1r[0]) * wc2r[0]; p3 += silu_f(c0[3] + bc1r[0]) * wc2r[0];
        p0 += silu_f(c1[0] + bc1r[1]) * wc2r[1]; p1 += silu_f(c1[1] + bc1r[1]) * wc2r[1];
        p2 += silu_f(c1[2] + bc1r[1]) * wc2r[1]; p3 += silu_f(c1[3] + bc1r[1]) * wc2r[1];
        p0 += silu_f(c2[0] + bc1r[2]) * wc2r[2]; p1 += silu_f(c2[1] + bc1r[2]) * wc2r[2];
        p2 += silu_f(c2[2] + bc1r[2]) * wc2r[2]; p3 += silu_f(c2[3] + bc1r[2]) * wc2r[2];
        p0 += silu_f(c3[0] + bc1r[3]) * wc2r[3]; p1 += silu_f(c3[1] + bc1r[3]) * wc2r[3];
        p2 += silu_f(c3[2] + bc1r[3]) * wc2r[3]; p3 += silu_f(c3[3] + bc1r[3]) * wc2r[3];
        // reduce over the 16 lanes of each group (lrow axis)
        #pragma unroll
        for (int mk = 1; mk < 16; mk <<= 1) {
            p0 += __shfl_xor(p0, mk);
            p1 += __shfl_xor(p1, mk);
            p2 += __shfl_xor(p2, mk);
            p3 += __shfl_xor(p3, mk);
        }
        if (lrow < 4) {
            float sel = (lrow == 0) ? p0 : (lrow == 1) ? p1 : (lrow == 2) ? p2 : p3;
            msg_lds[wave][tt * 16 + kg * 4 + lrow][16] = (__bf16)(cb2 + sel);
        }
        __builtin_amdgcn_wave_barrier();
    }

    // ---- per-lane: r*cw into LDS cols 16..18 ----
    float cwo = (float)msg_lds[wave][lane][16];
    msg_lds[wave][lane][16] = (__bf16)(rx * cwo);
    msg_lds[wave][lane][17] = (__bf16)(ry * cwo);
    msg_lds[wave][lane][18] = (__bf16)(rz * cwo);

    // ---- run detection (sorted by t) + distributed run-sum + atomics ----
    int t_next = __shfl_down(t_scan, 1);
    bool is_end = (lane == 63) || (t_next != t_scan);
    uint64_t mask = __ballot(is_end);
    int nr = __popcll(mask);
    if (is_end) {
        uint64_t below = mask & ((1ULL << lane) - 1ULL);
        int rid = __popcll(below);
        int st2 = (below == 0ULL) ? 0 : (64 - __builtin_clzll(below));  // prev end + 1
        run_t[wave][rid]  = t_scan;
        run_se[wave][rid] = (uint)((st2 << 8) | lane);
    }
    __builtin_amdgcn_wave_barrier();

    for (int task = lane; task < nr * NVALS; task += 64) {
        int rid = task / NVALS;
        int v   = task - rid * NVALS;
        int t   = run_t[wave][rid];
        if (t >= 0) {
            uint se = run_se[wave][rid];
            int st2 = (int)(se >> 8), en = (int)(se & 0xFFu);
            float sum = 0.f;
            for (int e = st2; e <= en; ++e) sum += (float)msg_lds[wave][e][v];
            if (v < 16) atomicAdd(&agg_msg[(size_t)t * MDIM + v], sum);
            else        atomicAdd(&agg_pos[(size_t)t * 3 + (v - 16)], sum);
        }
    }
}

// ---------------- MFMA node MLP + residual + pos update ----------------
__global__ void __launch_bounds__(256) node_mfma(
        float* __restrict__ x, float* __restrict__ pos,
        const float* __restrict__ agg_msg, const float* __restrict__ agg_pos,
        const bf16x8* __restrict__ WN1Fl, const bf16x8* __restrict__ WN2Fl,
        const float* __restrict__ bn1l, const float* __restrict__ bn2l, int N) {
    __shared__ __align__(16) __bf16 stg[4][16][136];
    int wave = threadIdx.x >> 6, lane = threadIdx.x & 63;
    int nb = blockIdx.x * 64 + wave * 16;
    int lrow = lane & 15, lkg = lane >> 4;
    int row = nb + lrow;
    int rc = (row < N) ? row : (N - 1);

    const float* xr = x + (size_t)rc * NDIM + lkg * 8;
    bf16x8 a0, a1, a2;
    #pragma unroll
    for (int j = 0; j < 8; ++j) { a0[j] = (__bf16)xr[j]; a1[j] = (__bf16)xr[32 + j]; }
    if (lkg < 2) {
        const float* mr = agg_msg + (size_t)rc * MDIM + lkg * 8;
        #pragma unroll
        for (int j = 0; j < 8; ++j) a2[j] = (__bf16)mr[j];
    } else {
        #pragma unroll
        for (int j = 0; j < 8; ++j) a2[j] = (__bf16)0.f;
    }

    f32x4 h[8];
    #pragma unroll
    for (int t = 0; t < 8; ++t) h[t] = (f32x4){0.f, 0.f, 0.f, 0.f};
    const bf16x8* b1 = WN1Fl + lane;
    #pragma unroll
    for (int t = 0; t < 8; ++t) {
        h[t] = MFMA16(a0, b1[(t * 3 + 0) * 64], h[t]);
        h[t] = MFMA16(a1, b1[(t * 3 + 1) * 64], h[t]);
        h[t] = MFMA16(a2, b1[(t * 3 + 2) * 64], h[t]);
    }
    #pragma unroll
    for (int t = 0; t < 8; ++t) {
        int col = t * 16 + lrow;
        float bias = bn1l[col];
        #pragma unroll
        for (int r = 0; r < 4; ++r)
            stg[wave][lkg * 4 + r][col] = (__bf16)silu_f(h[t][r] + bias);
    }
    __syncthreads();

    bf16x8 af[4];
    #pragma unroll
    for (int kt = 0; kt < 4; ++kt)
        af[kt] = *(const bf16x8*)&stg[wave][lrow][kt * 32 + lkg * 8];

    f32x4 o[4];
    #pragma unroll
    for (int t = 0; t < 4; ++t) o[t] = (f32x4){0.f, 0.f, 0.f, 0.f};
    const bf16x8* b2 = WN2Fl + lane;
    #pragma unroll
    for (int t = 0; t < 4; ++t) {
        #pragma unroll
        for (int kt = 0; kt < 4; ++kt)
            o[t] = MFMA16(af[kt], b2[(t * 4 + kt) * 64], o[t]);
    }

    int orow = nb + lkg * 4;
    #pragma unroll
    for (int t = 0; t < 4; ++t) {
        int col = t * 16 + lrow;
        float bias = bn2l[col];
        #pragma unroll
        for (int r = 0; r < 4; ++r) {
            int rr = orow + r;
            if (rr < N) x[(size_t)rr * NDIM + col] += o[t][r] + bias;
        }
    }
    if (threadIdx.x < 192) {
        long j = (long)blockIdx.x * 192 + threadIdx.x;
        if (j < (long)N * 3) pos[j] += agg_pos[j];
    }
}

// ---------------- host launch ----------------
extern "C" void kernel_launch(void* const* d_in, const int* in_sizes, int n_in,
                              void* d_out, int out_size, void* d_ws, size_t ws_size,
                              hipStream_t stream) {
    const int*   feats = (const int*)  d_in[0];
    const float* coors = (const float*)d_in[1];
    const int*   ei    = (const int*)  d_in[2];
    const float* emb   = (const float*)d_in[3];
    const float* We1   = (const float*)d_in[4];
    const float* be1   = (const float*)d_in[5];
    const float* We2   = (const float*)d_in[6];
    const float* be2   = (const float*)d_in[7];
    const float* Wc1   = (const float*)d_in[8];
    const float* bc1   = (const float*)d_in[9];
    const float* Wc2   = (const float*)d_in[10];
    const float* bc2   = (const float*)d_in[11];
    const float* Wn1   = (const float*)d_in[12];
    const float* bn1   = (const float*)d_in[13];
    const float* Wn2   = (const float*)d_in[14];
    const float* bn2   = (const float*)d_in[15];

    const int N = in_sizes[0];
    const int E = in_sizes[2] / 2;

    float* x   = (float*)d_out;                     // [N,64]
    float* pos = (float*)d_out + (size_t)N * NDIM;  // [N,3]

    // workspace layout
    char* w = (char*)d_ws;
    uint8_t* A8 = (uint8_t*)w;                                  // N*512
    size_t off = ((size_t)N * AB_STRIDE + 255) & ~(size_t)255;
    uint8_t* pkt = (uint8_t*)(w + off);                         // N*32
    off += ((size_t)N * PKT_STRIDE + 255) & ~(size_t)255;
    float* agg_msg = (float*)(w + off);                         // N*16
    off += ((size_t)N * MDIM * 4 + 255) & ~(size_t)255;
    float* agg_pos = (float*)(w + off);                         // N*3
    off += ((size_t)N * 3 * 4 + 255) & ~(size_t)255;
    uint2* sorted_st = (uint2*)(w + off);                       // E*8
    off += ((size_t)E * 8 + 255) & ~(size_t)255;
    int* cnt = (int*)(w + off);                                 // N
    off += ((size_t)N * 4 + 255) & ~(size_t)255;
    int* cursor = (int*)(w + off);                              // N
    off += ((size_t)N * 4 + 255) & ~(size_t)255;
    int* bsum = (int*)(w + off);                                // ceil(N/256)
    off += (((size_t)N / 256 + 2) * 4 + 255) & ~(size_t)255;
    __bf16* WE1F = (__bf16*)(w + off);
    off += ((size_t)NLAYER * WE1F_L * 2 + 255) & ~(size_t)255;
    __bf16* WN1F = (__bf16*)(w + off);
    off += ((size_t)NLAYER * WN1F_L * 2 + 255) & ~(size_t)255;
    __bf16* WN2F = (__bf16*)(w + off);
    off += ((size_t)NLAYER * WN2F_L * 2 + 255) & ~(size_t)255;
    __bf16* WE2F = (__bf16*)(w + off);
    off += ((size_t)NLAYER * WE2F_L * 2 + 255) & ~(size_t)255;
    __bf16* WC1F = (__bf16*)(w + off);
    (void)ws_size; (void)n_in; (void)out_size;

    {
        int total = NLAYER * (WE1F_L + WN1F_L + WN2F_L + WE2F_L + WC1F_L);
        prep_kernel<<<(total + 255) / 256, 256, 0, stream>>>(We1, Wn1, Wn2, We2, Wc1,
                                                             WE1F, WN1F, WN2F, WE2F, WC1F);
    }
    {
        int total = N * (NDIM + 3);
        init_kernel<<<(total + 255) / 256, 256, 0, stream>>>(feats, coors, emb, x, pos, N);
    }
    // counting sort by target (once; edge_index constant across layers)
    hipMemsetAsync(cnt, 0, (size_t)N * 4, stream);
    hist_kernel<<<(E + 255) / 256, 256, 0, stream>>>(ei, cnt, E);
    {
        int nb = (N + 255) / 256;
        scan_sum_kernel<<<nb, 256, 0, stream>>>(cnt, bsum, N);
        scan_top_kernel<<<1, 1024, 0, stream>>>(bsum, nb);
        scan_fin_kernel<<<nb, 256, 0, stream>>>(cnt, bsum, cursor, N);
    }
    scatter_kernel<<<(E + 255) / 256, 256, 0, stream>>>(ei, cursor, sorted_st, E);

    for (int l = 0; l < NLAYER; ++l) {
        const float* We1_l  = We1 + (size_t)l * EIN * EHD;
        const float* w128_l = We1_l + (size_t)128 * EHD;

        gemm_ab_mfma<<<(N + 31) / 32, 256, 0, stream>>>(
            x, pos, (const bf16x8*)(WE1F + (size_t)l * WE1F_L),
            be1 + (size_t)l * EHD, A8, pkt, agg_msg, agg_pos, N);

        edge_kernel<<<(E + 255) / 256, 256, 0, stream>>>(
            sorted_st, A8, pkt,
            (const bf16x8*)(WE2F + (size_t)l * WE2F_L),
            (const bf16x8*)(WC1F + (size_t)l * WC1F_L),
            be2 + (size_t)l * MDIM,
            bc1 + (size_t)l * CHD, Wc2 + (size_t)l * CHD, bc2 + l, w128_l,
            agg_msg, agg_pos, E);

        node_mfma<<<(N + 63) / 64, 256, 0, stream>>>(
            x, pos, agg_msg, agg_pos,
            (const bf16x8*)(WN1F + (size_t)l * WN1F_L),
            (const bf16x8*)(WN2F + (size_t)l * WN2F_L),
            bn1 + (size_t)l * NHD, bn2 + (size_t)l * NDIM, N);
    }
}